// Round 18
// baseline (324.343 us; speedup 1.0000x reference)
//
#include <hip/hip_runtime.h>
#include <hip/hip_fp16.h>

#define NN 100000
#define NE 1600000
#define NB 391        // ceil(NN/256)
#define NS 13         // src slices: slice = src >> 13
#define NSP1 14
#define SLICE_SHIFT 13
#define NSEG 391      // dst segments of 256 nodes: seg = dst >> 8
#define EPB 4096      // edges per fillA/seghist block
#define GRID_E 391    // ceil(NE/EPB)

__device__ __forceinline__ float rdlane(float v, int i) {
    return __uint_as_float(__builtin_amdgcn_readlane(__float_as_uint(v), (unsigned)i));
}

__device__ __forceinline__ void h4acc(float2 raw, float& ax, float& ay, float& az, float& aw) {
    __half2 lo = *reinterpret_cast<__half2*>(&raw.x);
    __half2 hi = *reinterpret_cast<__half2*>(&raw.y);
    float2 a = __half22float2(lo);
    float2 b = __half22float2(hi);
    ax += a.x; ay += a.y; az += b.x; aw += b.y;
}

// ===================== build phase A: segment sort (frozen from R17) =====================

__global__ __launch_bounds__(256) void seghist_k(const int* __restrict__ ei,
                                                 int* __restrict__ segcnt) {
    __shared__ int cnt[NSEG];
    for (int i = threadIdx.x; i < NSEG; i += 256) cnt[i] = 0;
    __syncthreads();
    int eb = blockIdx.x * EPB;
    int ee = (eb + EPB < NE) ? eb + EPB : NE;
    for (int e = eb + threadIdx.x; e < ee; e += 256)
        atomicAdd(&cnt[ei[NE + e] >> 8], 1);
    __syncthreads();
    for (int i = threadIdx.x; i < NSEG; i += 256)
        if (cnt[i]) atomicAdd(&segcnt[i], cnt[i]);
}

__global__ __launch_bounds__(512) void segscan_k(const int* __restrict__ segcnt,
                                                 int* __restrict__ segstart,
                                                 int* __restrict__ cursorA) {
    __shared__ int tmp[512];
    int t = threadIdx.x;
    int v = (t < NSEG) ? segcnt[t] : 0;
    tmp[t] = v;
    __syncthreads();
#pragma unroll
    for (int off = 1; off < 512; off <<= 1) {
        int u = (t >= off) ? tmp[t - off] : 0;
        __syncthreads();
        tmp[t] += u;
        __syncthreads();
    }
    if (t < NSEG) {
        int excl = tmp[t] - v;
        segstart[t] = excl;
        cursorA[t] = excl;
    }
    if (t == 0) segstart[NSEG] = NE;
}

__global__ __launch_bounds__(256) void fillA_k(const int* __restrict__ ei,
                                               int* __restrict__ cursorA,
                                               int* __restrict__ segbuf) {
    __shared__ int cnt[NSEG];
    __shared__ int base[NSEG];
    for (int i = threadIdx.x; i < NSEG; i += 256) cnt[i] = 0;
    __syncthreads();

    int eb = blockIdx.x * EPB;
    int pay[16], sb[16];
#pragma unroll
    for (int k = 0; k < 16; ++k) {
        int e = eb + k * 256 + threadIdx.x;
        sb[k] = -1;
        pay[k] = 0;
        if (e < NE) {
            int src = ei[e];
            int dst = ei[NE + e];
            int seg = dst >> 8;
            int off = atomicAdd(&cnt[seg], 1);
            pay[k] = ((dst & 255) << 17) | src;
            sb[k] = (seg << 12) | off;
        }
    }
    __syncthreads();
    for (int b = threadIdx.x; b < NSEG; b += 256)
        base[b] = cnt[b] ? atomicAdd(&cursorA[b], cnt[b]) : 0;
    __syncthreads();
#pragma unroll
    for (int k = 0; k < 16; ++k) {
        if (sb[k] >= 0) {
            int seg = sb[k] >> 12;
            int off = sb[k] & 4095;
            segbuf[base[seg] + off] = pay[k];
        }
    }
}

// ===================== build phase B (frozen from R17) =====================

__global__ __launch_bounds__(256) void deghist_k(const int* __restrict__ segbuf,
                                                 const int* __restrict__ segstart,
                                                 int* __restrict__ deg2) {
    __shared__ int cnt[256 * NS];
    for (int i = threadIdx.x; i < 256 * NS; i += 256) cnt[i] = 0;
    __syncthreads();
    int s0 = segstart[blockIdx.x], s1 = segstart[blockIdx.x + 1];
    for (int e = s0 + threadIdx.x; e < s1; e += 256) {
        int pk = segbuf[e];
        int l = pk >> 17;
        int src = pk & 0x1FFFF;
        atomicAdd(&cnt[l * NS + (src >> SLICE_SHIFT)], 1);
    }
    __syncthreads();
    int n = blockIdx.x * 256 + threadIdx.x;
    if (n < NN) {
#pragma unroll
        for (int s = 0; s < NS; ++s)
            deg2[n * NS + s] = cnt[threadIdx.x * NS + s];
    }
}

__global__ __launch_bounds__(256) void scan1_k(const int* __restrict__ deg2,
                                               int* __restrict__ scanned,
                                               int* __restrict__ bsums) {
    __shared__ int tmp[256];
    int i = blockIdx.x * 256 + threadIdx.x;
    int v = 0;
    if (i < NN) {
#pragma unroll
        for (int k = 0; k < NS; ++k) v += deg2[i * NS + k];
    }
    tmp[threadIdx.x] = v;
    __syncthreads();
#pragma unroll
    for (int off = 1; off < 256; off <<= 1) {
        int t = (threadIdx.x >= off) ? tmp[threadIdx.x - off] : 0;
        __syncthreads();
        tmp[threadIdx.x] += t;
        __syncthreads();
    }
    if (i < NN) scanned[i] = tmp[threadIdx.x];
    if (threadIdx.x == 255) bsums[blockIdx.x] = tmp[255];
}

__global__ __launch_bounds__(512) void scan2_k(int* __restrict__ bsums) {
    __shared__ int tmp[512];
    int v = (threadIdx.x < NB) ? bsums[threadIdx.x] : 0;
    tmp[threadIdx.x] = v;
    __syncthreads();
#pragma unroll
    for (int off = 1; off < 512; off <<= 1) {
        int t = (threadIdx.x >= off) ? tmp[threadIdx.x - off] : 0;
        __syncthreads();
        tmp[threadIdx.x] += t;
        __syncthreads();
    }
    if (threadIdx.x < NB) bsums[threadIdx.x] = tmp[threadIdx.x];
}

__global__ __launch_bounds__(256) void scan3b_k(const int* __restrict__ scanned,
                                                const int* __restrict__ bsums,
                                                const int* __restrict__ deg2,
                                                int* __restrict__ P) {
    int i = blockIdx.x * 256 + threadIdx.x;
    if (i < NN) {
        int d = 0;
#pragma unroll
        for (int k = 0; k < NS; ++k) d += deg2[i * NS + k];
        int incl = scanned[i] + (blockIdx.x ? bsums[blockIdx.x - 1] : 0);
        int run = incl - d;
        P[i * NSP1 + 0] = run;
#pragma unroll
        for (int s = 0; s < NS; ++s) {
            P[i * NSP1 + s + 1] = run;
            run += deg2[i * NS + s];
        }
        if (i == NN - 1) P[NN * NSP1] = incl;   // sentinel = NE
    }
}

__global__ __launch_bounds__(256) void fillB_k(const int* __restrict__ segbuf,
                                               const int* __restrict__ segstart,
                                               const int* __restrict__ P,
                                               int* __restrict__ col) {
    __shared__ int cur[256 * NS];
    int n = blockIdx.x * 256 + threadIdx.x;
    if (n < NN) {
#pragma unroll
        for (int s = 0; s < NS; ++s)
            cur[threadIdx.x * NS + s] = P[n * NSP1 + s + 1];
    }
    __syncthreads();
    int s0 = segstart[blockIdx.x], s1 = segstart[blockIdx.x + 1];
    for (int e = s0 + threadIdx.x; e < s1; e += 256) {
        int pk = segbuf[e];
        int l = pk >> 17;
        int src = pk & 0x1FFFF;
        int pos = atomicAdd(&cur[l * NS + (src >> SLICE_SHIFT)], 1);
        col[pos] = src;
    }
}

__global__ __launch_bounds__(256) void cvt_k(const float2* __restrict__ x2,
                                             __half2* __restrict__ x16) {
    int i = blockIdx.x * 256 + threadIdx.x;
    if (i < NN * 16) {
        float2 v = x2[i];
        x16[i] = __floats2half2_rn(v.x, v.y);
    }
}

// ===================== per-node gather helpers (frozen gather structure) =====================

// 32-ch gather: cq = lane&7, g = lane>>3; returns (avx,avy,avz,avw) pre-self
__device__ __forceinline__ float4 gather32(const float2* __restrict__ x16f2,
                                           const int* __restrict__ col,
                                           int s0, int s1, int cq, int g) {
    float ax0 = 0.f, ay0 = 0.f, az0 = 0.f, aw0 = 0.f;
    float ax1 = 0.f, ay1 = 0.f, az1 = 0.f, aw1 = 0.f;
    int e = s0;
    for (; e + 15 < s1; e += 16) {
        int c0 = col[e + g];
        int c1 = col[e + 8 + g];
        float2 f0 = x16f2[(size_t)c0 * 8 + cq];
        float2 f1 = x16f2[(size_t)c1 * 8 + cq];
        h4acc(f0, ax0, ay0, az0, aw0);
        h4acc(f1, ax1, ay1, az1, aw1);
    }
    for (int ee = e + g; ee < s1; ee += 8) {
        float2 f = x16f2[(size_t)col[ee] * 8 + cq];
        h4acc(f, ax0, ay0, az0, aw0);
    }
    float avx = ax0 + ax1, avy = ay0 + ay1, avz = az0 + az1, avw = aw0 + aw1;
    avx += __shfl_xor(avx, 8);  avy += __shfl_xor(avy, 8);
    avz += __shfl_xor(avz, 8);  avw += __shfl_xor(avw, 8);
    avx += __shfl_xor(avx, 16); avy += __shfl_xor(avy, 16);
    avz += __shfl_xor(avz, 16); avw += __shfl_xor(avw, 16);
    avx += __shfl_xor(avx, 32); avy += __shfl_xor(avy, 32);
    avz += __shfl_xor(avz, 32); avw += __shfl_xor(avw, 32);
    return make_float4(avx, avy, avz, avw);
}

// 64-ch gather: cq = lane&15, g = lane>>4
__device__ __forceinline__ float4 gather64(const float2* __restrict__ hf2,
                                           const int* __restrict__ col,
                                           int s0, int s1, int cq, int g) {
    float ax0 = 0.f, ay0 = 0.f, az0 = 0.f, aw0 = 0.f;
    float ax1 = 0.f, ay1 = 0.f, az1 = 0.f, aw1 = 0.f;
    float ax2 = 0.f, ay2 = 0.f, az2 = 0.f, aw2 = 0.f;
    float ax3 = 0.f, ay3 = 0.f, az3 = 0.f, aw3 = 0.f;
    int e = s0;
    for (; e + 15 < s1; e += 16) {
        int c0 = col[e + g];
        int c1 = col[e + 4 + g];
        int c2 = col[e + 8 + g];
        int c3 = col[e + 12 + g];
        float2 f0 = hf2[(size_t)c0 * 16 + cq];
        float2 f1 = hf2[(size_t)c1 * 16 + cq];
        float2 f2 = hf2[(size_t)c2 * 16 + cq];
        float2 f3 = hf2[(size_t)c3 * 16 + cq];
        h4acc(f0, ax0, ay0, az0, aw0);
        h4acc(f1, ax1, ay1, az1, aw1);
        h4acc(f2, ax2, ay2, az2, aw2);
        h4acc(f3, ax3, ay3, az3, aw3);
    }
    for (int ee = e + g; ee < s1; ee += 4) {
        float2 f = hf2[(size_t)col[ee] * 16 + cq];
        h4acc(f, ax0, ay0, az0, aw0);
    }
    float avx = (ax0 + ax1) + (ax2 + ax3);
    float avy = (ay0 + ay1) + (ay2 + ay3);
    float avz = (az0 + az1) + (az2 + az3);
    float avw = (aw0 + aw1) + (aw2 + aw3);
    avx += __shfl_xor(avx, 16); avy += __shfl_xor(avy, 16);
    avz += __shfl_xor(avz, 16); avw += __shfl_xor(avw, 16);
    avx += __shfl_xor(avx, 32); avy += __shfl_xor(avy, 32);
    avz += __shfl_xor(avz, 32); avw += __shfl_xor(avw, 32);
    return make_float4(avx, avy, avz, avw);
}

// ============ layer 1: 4-node batched gather + MLP1 -> h16 ============
__global__ __launch_bounds__(256) void fused1(const float* __restrict__ x,
                                              const float2* __restrict__ x16f2,
                                              const int* __restrict__ P,
                                              const int* __restrict__ col,
                                              const float* __restrict__ W1,
                                              const float* __restrict__ b1,
                                              const float* __restrict__ W2,
                                              const float* __restrict__ b2,
                                              __half* __restrict__ h16) {
    __shared__ float W1s[32 * 64];
    __shared__ float W2s[64 * 64];
    __shared__ float b1s[64];
    __shared__ float b2s[64];
    for (int i = threadIdx.x; i < 32 * 64; i += 256) W1s[i] = W1[i];
    for (int i = threadIdx.x; i < 64 * 64; i += 256) W2s[i] = W2[i];
    if (threadIdx.x < 64) {
        b1s[threadIdx.x] = b1[threadIdx.x];
        b2s[threadIdx.x] = b2[threadIdx.x];
    }
    __syncthreads();

    int lane = threadIdx.x & 63;
    int cq = lane & 7;
    int g = lane >> 3;
    int gw = blockIdx.x * 4 + (threadIdx.x >> 6);
    int stride = gridDim.x * 16;           // waves * 4 nodes

    for (int nb = gw * 4; nb < NN; nb += stride) {   // NN%4==0, nb%4==0 -> all 4 valid
        float4 A0 = gather32(x16f2, col, P[nb * NSP1],       P[(nb + 1) * NSP1], cq, g);
        float4 A1 = gather32(x16f2, col, P[(nb + 1) * NSP1], P[(nb + 2) * NSP1], cq, g);
        float4 A2 = gather32(x16f2, col, P[(nb + 2) * NSP1], P[(nb + 3) * NSP1], cq, g);
        float4 A3 = gather32(x16f2, col, P[(nb + 3) * NSP1], P[(nb + 4) * NSP1], cq, g);
        float4 sf0 = ((const float4*)x)[(size_t)nb * 8 + cq];
        float4 sf1 = ((const float4*)x)[(size_t)(nb + 1) * 8 + cq];
        float4 sf2 = ((const float4*)x)[(size_t)(nb + 2) * 8 + cq];
        float4 sf3 = ((const float4*)x)[(size_t)(nb + 3) * 8 + cq];
        A0.x += sf0.x; A0.y += sf0.y; A0.z += sf0.z; A0.w += sf0.w;
        A1.x += sf1.x; A1.y += sf1.y; A1.z += sf1.z; A1.w += sf1.w;
        A2.x += sf2.x; A2.y += sf2.y; A2.z += sf2.z; A2.w += sf2.w;
        A3.x += sf3.x; A3.y += sf3.y; A3.z += sf3.z; A3.w += sf3.w;

        // layer A: one weight sweep feeds 4 nodes
        float bb = b1s[lane];
        float sa0 = bb, sb0 = 0.f, sa1 = bb, sb1 = 0.f;
        float sa2 = bb, sb2 = 0.f, sa3 = bb, sb3 = 0.f;
#pragma unroll
        for (int i = 0; i < 8; ++i) {
            float w0 = W1s[(4 * i) * 64 + lane];
            float w1 = W1s[(4 * i + 1) * 64 + lane];
            float w2 = W1s[(4 * i + 2) * 64 + lane];
            float w3 = W1s[(4 * i + 3) * 64 + lane];
            sa0 = fmaf(rdlane(A0.x, i), w0, sa0); sb0 = fmaf(rdlane(A0.y, i), w1, sb0);
            sa0 = fmaf(rdlane(A0.z, i), w2, sa0); sb0 = fmaf(rdlane(A0.w, i), w3, sb0);
            sa1 = fmaf(rdlane(A1.x, i), w0, sa1); sb1 = fmaf(rdlane(A1.y, i), w1, sb1);
            sa1 = fmaf(rdlane(A1.z, i), w2, sa1); sb1 = fmaf(rdlane(A1.w, i), w3, sb1);
            sa2 = fmaf(rdlane(A2.x, i), w0, sa2); sb2 = fmaf(rdlane(A2.y, i), w1, sb2);
            sa2 = fmaf(rdlane(A2.z, i), w2, sa2); sb2 = fmaf(rdlane(A2.w, i), w3, sb2);
            sa3 = fmaf(rdlane(A3.x, i), w0, sa3); sb3 = fmaf(rdlane(A3.y, i), w1, sb3);
            sa3 = fmaf(rdlane(A3.z, i), w2, sa3); sb3 = fmaf(rdlane(A3.w, i), w3, sb3);
        }
        float t0 = fmaxf(sa0 + sb0, 0.f);
        float t1 = fmaxf(sa1 + sb1, 0.f);
        float t2 = fmaxf(sa2 + sb2, 0.f);
        float t3 = fmaxf(sa3 + sb3, 0.f);

        // layer B
        float bb2v = b2s[lane];
        float o0a = bb2v, o0b = 0.f, o1a = bb2v, o1b = 0.f;
        float o2a = bb2v, o2b = 0.f, o3a = bb2v, o3b = 0.f;
#pragma unroll
        for (int j = 0; j < 64; j += 2) {
            float w0 = W2s[j * 64 + lane];
            float w1 = W2s[(j + 1) * 64 + lane];
            o0a = fmaf(rdlane(t0, j), w0, o0a); o0b = fmaf(rdlane(t0, j + 1), w1, o0b);
            o1a = fmaf(rdlane(t1, j), w0, o1a); o1b = fmaf(rdlane(t1, j + 1), w1, o1b);
            o2a = fmaf(rdlane(t2, j), w0, o2a); o2b = fmaf(rdlane(t2, j + 1), w1, o2b);
            o3a = fmaf(rdlane(t3, j), w0, o3a); o3b = fmaf(rdlane(t3, j + 1), w1, o3b);
        }
        h16[(size_t)nb * 64 + lane]       = __float2half(fmaxf(o0a + o0b, 0.f));
        h16[(size_t)(nb + 1) * 64 + lane] = __float2half(fmaxf(o1a + o1b, 0.f));
        h16[(size_t)(nb + 2) * 64 + lane] = __float2half(fmaxf(o2a + o2b, 0.f));
        h16[(size_t)(nb + 3) * 64 + lane] = __float2half(fmaxf(o3a + o3b, 0.f));
    }
}

// ============ layer 2: 4-node batched gather + MLP2 -> out ============
__global__ __launch_bounds__(256) void fused2(const float2* __restrict__ hf2,
                                              const int* __restrict__ P,
                                              const int* __restrict__ col,
                                              const float* __restrict__ W3,
                                              const float* __restrict__ b3,
                                              const float* __restrict__ W4,
                                              const float* __restrict__ b4,
                                              float* __restrict__ out) {
    __shared__ float W3s[64 * 64];
    __shared__ float W4s[64 * 32];
    __shared__ float b3s[64];
    __shared__ float b4s[32];
    for (int i = threadIdx.x; i < 64 * 64; i += 256) W3s[i] = W3[i];
    for (int i = threadIdx.x; i < 64 * 32; i += 256) W4s[i] = W4[i];
    if (threadIdx.x < 64) b3s[threadIdx.x] = b3[threadIdx.x];
    if (threadIdx.x < 32) b4s[threadIdx.x] = b4[threadIdx.x];
    __syncthreads();

    int lane = threadIdx.x & 63;
    int cq = lane & 15;
    int g = lane >> 4;
    int gw = blockIdx.x * 4 + (threadIdx.x >> 6);
    int stride = gridDim.x * 16;

    for (int nb = gw * 4; nb < NN; nb += stride) {
        float4 A0 = gather64(hf2, col, P[nb * NSP1],       P[(nb + 1) * NSP1], cq, g);
        float4 A1 = gather64(hf2, col, P[(nb + 1) * NSP1], P[(nb + 2) * NSP1], cq, g);
        float4 A2 = gather64(hf2, col, P[(nb + 2) * NSP1], P[(nb + 3) * NSP1], cq, g);
        float4 A3 = gather64(hf2, col, P[(nb + 3) * NSP1], P[(nb + 4) * NSP1], cq, g);
        // self rows (fp16)
        {
            float2 r0 = hf2[(size_t)nb * 16 + cq];
            float2 r1 = hf2[(size_t)(nb + 1) * 16 + cq];
            float2 r2 = hf2[(size_t)(nb + 2) * 16 + cq];
            float2 r3 = hf2[(size_t)(nb + 3) * 16 + cq];
            h4acc(r0, A0.x, A0.y, A0.z, A0.w);
            h4acc(r1, A1.x, A1.y, A1.z, A1.w);
            h4acc(r2, A2.x, A2.y, A2.z, A2.w);
            h4acc(r3, A3.x, A3.y, A3.z, A3.w);
        }

        float bb = b3s[lane];
        float sa0 = bb, sb0 = 0.f, sa1 = bb, sb1 = 0.f;
        float sa2 = bb, sb2 = 0.f, sa3 = bb, sb3 = 0.f;
#pragma unroll
        for (int i = 0; i < 16; ++i) {
            float w0 = W3s[(4 * i) * 64 + lane];
            float w1 = W3s[(4 * i + 1) * 64 + lane];
            float w2 = W3s[(4 * i + 2) * 64 + lane];
            float w3 = W3s[(4 * i + 3) * 64 + lane];
            sa0 = fmaf(rdlane(A0.x, i), w0, sa0); sb0 = fmaf(rdlane(A0.y, i), w1, sb0);
            sa0 = fmaf(rdlane(A0.z, i), w2, sa0); sb0 = fmaf(rdlane(A0.w, i), w3, sb0);
            sa1 = fmaf(rdlane(A1.x, i), w0, sa1); sb1 = fmaf(rdlane(A1.y, i), w1, sb1);
            sa1 = fmaf(rdlane(A1.z, i), w2, sa1); sb1 = fmaf(rdlane(A1.w, i), w3, sb1);
            sa2 = fmaf(rdlane(A2.x, i), w0, sa2); sb2 = fmaf(rdlane(A2.y, i), w1, sb2);
            sa2 = fmaf(rdlane(A2.z, i), w2, sa2); sb2 = fmaf(rdlane(A2.w, i), w3, sb2);
            sa3 = fmaf(rdlane(A3.x, i), w0, sa3); sb3 = fmaf(rdlane(A3.y, i), w1, sb3);
            sa3 = fmaf(rdlane(A3.z, i), w2, sa3); sb3 = fmaf(rdlane(A3.w, i), w3, sb3);
        }
        float t0 = fmaxf(sa0 + sb0, 0.f);
        float t1 = fmaxf(sa1 + sb1, 0.f);
        float t2 = fmaxf(sa2 + sb2, 0.f);
        float t3 = fmaxf(sa3 + sb3, 0.f);

        float bb4 = b4s[lane & 31];
        float o0a = bb4, o0b = 0.f, o1a = bb4, o1b = 0.f;
        float o2a = bb4, o2b = 0.f, o3a = bb4, o3b = 0.f;
#pragma unroll
        for (int j = 0; j < 64; j += 2) {
            float w0 = W4s[j * 32 + (lane & 31)];
            float w1 = W4s[(j + 1) * 32 + (lane & 31)];
            o0a = fmaf(rdlane(t0, j), w0, o0a); o0b = fmaf(rdlane(t0, j + 1), w1, o0b);
            o1a = fmaf(rdlane(t1, j), w0, o1a); o1b = fmaf(rdlane(t1, j + 1), w1, o1b);
            o2a = fmaf(rdlane(t2, j), w0, o2a); o2b = fmaf(rdlane(t2, j + 1), w1, o2b);
            o3a = fmaf(rdlane(t3, j), w0, o3a); o3b = fmaf(rdlane(t3, j + 1), w1, o3b);
        }
        if (lane < 32) {
            out[(size_t)nb * 32 + lane]       = o0a + o0b;
            out[(size_t)(nb + 1) * 32 + lane] = o1a + o1b;
            out[(size_t)(nb + 2) * 32 + lane] = o2a + o2b;
            out[(size_t)(nb + 3) * 32 + lane] = o3a + o3b;
        }
    }
}

extern "C" void kernel_launch(void* const* d_in, const int* in_sizes, int n_in,
                              void* d_out, int out_size, void* d_ws, size_t ws_size,
                              hipStream_t stream) {
    const float* x  = (const float*)d_in[0];
    const int*   ei = (const int*)d_in[1];
    const float* W1 = (const float*)d_in[2];
    const float* b1 = (const float*)d_in[3];
    const float* W2 = (const float*)d_in[4];
    const float* b2 = (const float*)d_in[5];
    const float* W3 = (const float*)d_in[6];
    const float* b3 = (const float*)d_in[7];
    const float* W4 = (const float*)d_in[8];
    const float* b4 = (const float*)d_in[9];
    float* out = (float*)d_out;

    char* ws = (char*)d_ws;
    __half* h16   = (__half*)ws;                      ws += (size_t)NN * 64 * 2;           // 12.8 MB
    __half* x16   = (__half*)ws;                      ws += (size_t)NN * 32 * 2;           // 6.4 MB
    int*   col    = (int*)ws;                         ws += (size_t)NE * 4;                // 6.4 MB
    int*   P      = (int*)ws;                         ws += (size_t)(NN * NSP1 + 1) * 4;   // 5.6 MB
    int*   deg2   = (int*)ws;                         ws += (size_t)NN * NS * 4;           // 5.2 MB
    int*   segbuf = (int*)ws;                         ws += (size_t)NE * 4;                // 6.4 MB
    int* scanned  = (int*)ws;                         ws += (size_t)NN * 4;
    int*   bsums  = (int*)ws;                         ws += (size_t)NB * 4;
    int*  segcnt  = (int*)ws;                         ws += (size_t)NSEG * 4;
    int* segstart = (int*)ws;                         ws += (size_t)(NSEG + 1) * 4;
    int* cursorA  = (int*)ws;                         ws += (size_t)NSEG * 4;

    // ---- build: two-phase LDS-staged radix ----
    hipMemsetAsync(segcnt, 0, (size_t)NSEG * 4, stream);
    cvt_k<<<(NN * 16 + 255) / 256, 256, 0, stream>>>((const float2*)x, (__half2*)x16);
    seghist_k<<<GRID_E, 256, 0, stream>>>(ei, segcnt);
    segscan_k<<<1, 512, 0, stream>>>(segcnt, segstart, cursorA);
    fillA_k<<<GRID_E, 256, 0, stream>>>(ei, cursorA, segbuf);
    deghist_k<<<NSEG, 256, 0, stream>>>(segbuf, segstart, deg2);
    scan1_k<<<NB, 256, 0, stream>>>(deg2, scanned, bsums);
    scan2_k<<<1, 512, 0, stream>>>(bsums);
    scan3b_k<<<NB, 256, 0, stream>>>(scanned, bsums, deg2, P);
    fillB_k<<<NSEG, 256, 0, stream>>>(segbuf, segstart, P, col);

    // ---- fused layers: 4-node-batched MLP ----
    fused1<<<1536, 256, 0, stream>>>(x, (const float2*)x16, P, col,
                                     W1, b1, W2, b2, h16);
    fused2<<<1536, 256, 0, stream>>>((const float2*)h16, P, col,
                                     W3, b3, W4, b4, out);
}

// Round 20
// 264.777 us; speedup vs baseline: 1.2250x; 1.2250x over previous
//
#include <hip/hip_runtime.h>
#include <hip/hip_fp16.h>

#define NN 100000
#define NE 1600000
#define NB 391        // ceil(NN/256)
#define NS 13         // src slices: slice = src >> 13
#define NSP1 14
#define SLICE_SHIFT 13
#define NSEG 391      // dst segments of 256 nodes: seg = dst >> 8
#define EPB 4096      // edges per fillA/seghist block
#define GRID_E 391    // ceil(NE/EPB)

typedef _Float16 h2_t __attribute__((ext_vector_type(2)));

__device__ __forceinline__ unsigned pkh2(float lo, float hi) {
    auto v = __builtin_amdgcn_cvt_pkrtz(lo, hi);   // __fp16 ext_vector(2)
    unsigned u; __builtin_memcpy(&u, &v, 4); return u;
}
__device__ __forceinline__ float fdot2u(unsigned a, unsigned b, float c) {
    h2_t x, y; __builtin_memcpy(&x, &a, 4); __builtin_memcpy(&y, &b, 4);
    return __builtin_amdgcn_fdot2(x, y, c, false);
}
__device__ __forceinline__ unsigned rdlaneu(unsigned v, int i) {
    return (unsigned)__builtin_amdgcn_readlane((int)v, i);
}

__device__ __forceinline__ void h4acc(float2 raw, float& ax, float& ay, float& az, float& aw) {
    __half2 lo = *reinterpret_cast<__half2*>(&raw.x);
    __half2 hi = *reinterpret_cast<__half2*>(&raw.y);
    float2 a = __half22float2(lo);
    float2 b = __half22float2(hi);
    ax += a.x; ay += a.y; az += b.x; aw += b.y;
}

// ===================== build phase A: segment sort (frozen) =====================

__global__ __launch_bounds__(256) void seghist_k(const int* __restrict__ ei,
                                                 int* __restrict__ segcnt) {
    __shared__ int cnt[NSEG];
    for (int i = threadIdx.x; i < NSEG; i += 256) cnt[i] = 0;
    __syncthreads();
    int eb = blockIdx.x * EPB;
    int ee = (eb + EPB < NE) ? eb + EPB : NE;
    for (int e = eb + threadIdx.x; e < ee; e += 256)
        atomicAdd(&cnt[ei[NE + e] >> 8], 1);
    __syncthreads();
    for (int i = threadIdx.x; i < NSEG; i += 256)
        if (cnt[i]) atomicAdd(&segcnt[i], cnt[i]);
}

__global__ __launch_bounds__(512) void segscan_k(const int* __restrict__ segcnt,
                                                 int* __restrict__ segstart,
                                                 int* __restrict__ cursorA) {
    __shared__ int tmp[512];
    int t = threadIdx.x;
    int v = (t < NSEG) ? segcnt[t] : 0;
    tmp[t] = v;
    __syncthreads();
#pragma unroll
    for (int off = 1; off < 512; off <<= 1) {
        int u = (t >= off) ? tmp[t - off] : 0;
        __syncthreads();
        tmp[t] += u;
        __syncthreads();
    }
    if (t < NSEG) {
        int excl = tmp[t] - v;
        segstart[t] = excl;
        cursorA[t] = excl;
    }
    if (t == 0) segstart[NSEG] = NE;
}

__global__ __launch_bounds__(256) void fillA_k(const int* __restrict__ ei,
                                               int* __restrict__ cursorA,
                                               int* __restrict__ segbuf) {
    __shared__ int cnt[NSEG];
    __shared__ int base[NSEG];
    for (int i = threadIdx.x; i < NSEG; i += 256) cnt[i] = 0;
    __syncthreads();

    int eb = blockIdx.x * EPB;
    int pay[16], sb[16];
#pragma unroll
    for (int k = 0; k < 16; ++k) {
        int e = eb + k * 256 + threadIdx.x;
        sb[k] = -1;
        pay[k] = 0;
        if (e < NE) {
            int src = ei[e];
            int dst = ei[NE + e];
            int seg = dst >> 8;
            int off = atomicAdd(&cnt[seg], 1);
            pay[k] = ((dst & 255) << 17) | src;
            sb[k] = (seg << 12) | off;
        }
    }
    __syncthreads();
    for (int b = threadIdx.x; b < NSEG; b += 256)
        base[b] = cnt[b] ? atomicAdd(&cursorA[b], cnt[b]) : 0;
    __syncthreads();
#pragma unroll
    for (int k = 0; k < 16; ++k) {
        if (sb[k] >= 0) {
            int seg = sb[k] >> 12;
            int off = sb[k] & 4095;
            segbuf[base[seg] + off] = pay[k];
        }
    }
}

// ===================== build phase B (frozen) =====================

__global__ __launch_bounds__(256) void deghist_k(const int* __restrict__ segbuf,
                                                 const int* __restrict__ segstart,
                                                 int* __restrict__ deg2) {
    __shared__ int cnt[256 * NS];
    for (int i = threadIdx.x; i < 256 * NS; i += 256) cnt[i] = 0;
    __syncthreads();
    int s0 = segstart[blockIdx.x], s1 = segstart[blockIdx.x + 1];
    for (int e = s0 + threadIdx.x; e < s1; e += 256) {
        int pk = segbuf[e];
        int l = pk >> 17;
        int src = pk & 0x1FFFF;
        atomicAdd(&cnt[l * NS + (src >> SLICE_SHIFT)], 1);
    }
    __syncthreads();
    int n = blockIdx.x * 256 + threadIdx.x;
    if (n < NN) {
#pragma unroll
        for (int s = 0; s < NS; ++s)
            deg2[n * NS + s] = cnt[threadIdx.x * NS + s];
    }
}

__global__ __launch_bounds__(256) void scan1_k(const int* __restrict__ deg2,
                                               int* __restrict__ scanned,
                                               int* __restrict__ bsums) {
    __shared__ int tmp[256];
    int i = blockIdx.x * 256 + threadIdx.x;
    int v = 0;
    if (i < NN) {
#pragma unroll
        for (int k = 0; k < NS; ++k) v += deg2[i * NS + k];
    }
    tmp[threadIdx.x] = v;
    __syncthreads();
#pragma unroll
    for (int off = 1; off < 256; off <<= 1) {
        int t = (threadIdx.x >= off) ? tmp[threadIdx.x - off] : 0;
        __syncthreads();
        tmp[threadIdx.x] += t;
        __syncthreads();
    }
    if (i < NN) scanned[i] = tmp[threadIdx.x];
    if (threadIdx.x == 255) bsums[blockIdx.x] = tmp[255];
}

__global__ __launch_bounds__(512) void scan2_k(int* __restrict__ bsums) {
    __shared__ int tmp[512];
    int v = (threadIdx.x < NB) ? bsums[threadIdx.x] : 0;
    tmp[threadIdx.x] = v;
    __syncthreads();
#pragma unroll
    for (int off = 1; off < 512; off <<= 1) {
        int t = (threadIdx.x >= off) ? tmp[threadIdx.x - off] : 0;
        __syncthreads();
        tmp[threadIdx.x] += t;
        __syncthreads();
    }
    if (threadIdx.x < NB) bsums[threadIdx.x] = tmp[threadIdx.x];
}

__global__ __launch_bounds__(256) void scan3b_k(const int* __restrict__ scanned,
                                                const int* __restrict__ bsums,
                                                const int* __restrict__ deg2,
                                                int* __restrict__ P) {
    int i = blockIdx.x * 256 + threadIdx.x;
    if (i < NN) {
        int d = 0;
#pragma unroll
        for (int k = 0; k < NS; ++k) d += deg2[i * NS + k];
        int incl = scanned[i] + (blockIdx.x ? bsums[blockIdx.x - 1] : 0);
        int run = incl - d;
        P[i * NSP1 + 0] = run;
#pragma unroll
        for (int s = 0; s < NS; ++s) {
            P[i * NSP1 + s + 1] = run;
            run += deg2[i * NS + s];
        }
        if (i == NN - 1) P[NN * NSP1] = incl;   // sentinel = NE
    }
}

__global__ __launch_bounds__(256) void fillB_k(const int* __restrict__ segbuf,
                                               const int* __restrict__ segstart,
                                               const int* __restrict__ P,
                                               int* __restrict__ col) {
    __shared__ int cur[256 * NS];
    int n = blockIdx.x * 256 + threadIdx.x;
    if (n < NN) {
#pragma unroll
        for (int s = 0; s < NS; ++s)
            cur[threadIdx.x * NS + s] = P[n * NSP1 + s + 1];
    }
    __syncthreads();
    int s0 = segstart[blockIdx.x], s1 = segstart[blockIdx.x + 1];
    for (int e = s0 + threadIdx.x; e < s1; e += 256) {
        int pk = segbuf[e];
        int l = pk >> 17;
        int src = pk & 0x1FFFF;
        int pos = atomicAdd(&cur[l * NS + (src >> SLICE_SHIFT)], 1);
        col[pos] = src;
    }
}

__global__ __launch_bounds__(256) void cvt_k(const float2* __restrict__ x2,
                                             __half2* __restrict__ x16) {
    int i = blockIdx.x * 256 + threadIdx.x;
    if (i < NN * 16) {
        float2 v = x2[i];
        x16[i] = __floats2half2_rn(v.x, v.y);
    }
}

// pack weight pairs to half2: Wp[p][j] = (W[2p][j], W[2p+1][j])
__global__ __launch_bounds__(256) void packw_k(const float* __restrict__ W1,
                                               const float* __restrict__ W2,
                                               const float* __restrict__ W3,
                                               const float* __restrict__ W4,
                                               unsigned* __restrict__ W1p,
                                               unsigned* __restrict__ W2p,
                                               unsigned* __restrict__ W3p,
                                               unsigned* __restrict__ W4p) {
    int i = blockIdx.x * 256 + threadIdx.x;
    if (i < 16 * 64) {
        int p = i >> 6, j = i & 63;
        W1p[i] = pkh2(W1[(2 * p) * 64 + j], W1[(2 * p + 1) * 64 + j]);
    }
    if (i < 32 * 64) {
        int p = i >> 6, j = i & 63;
        W2p[i] = pkh2(W2[(2 * p) * 64 + j], W2[(2 * p + 1) * 64 + j]);
        W3p[i] = pkh2(W3[(2 * p) * 64 + j], W3[(2 * p + 1) * 64 + j]);
    }
    if (i < 32 * 32) {
        int p = i >> 5, j = i & 31;
        W4p[i] = pkh2(W4[(2 * p) * 32 + j], W4[(2 * p + 1) * 32 + j]);
    }
}

// ============ layer 1: half4 gather(x16) + dot2-MLP1 -> h16 ============
// gather frozen from R17: cq = lane&7 (ch quad), g = lane>>3 (edge slot).
__global__ __launch_bounds__(256) void fused1(const float* __restrict__ x,
                                              const float2* __restrict__ x16f2,
                                              const int* __restrict__ P,
                                              const int* __restrict__ col,
                                              const unsigned* __restrict__ W1p,
                                              const float* __restrict__ b1,
                                              const unsigned* __restrict__ W2p,
                                              const float* __restrict__ b2,
                                              __half* __restrict__ h16) {
    __shared__ unsigned W1s[16 * 64];   // 4 KB
    __shared__ unsigned W2s[32 * 64];   // 8 KB
    __shared__ float b1s[64];
    __shared__ float b2s[64];
    for (int i = threadIdx.x; i < 16 * 64; i += 256) W1s[i] = W1p[i];
    for (int i = threadIdx.x; i < 32 * 64; i += 256) W2s[i] = W2p[i];
    if (threadIdx.x < 64) {
        b1s[threadIdx.x] = b1[threadIdx.x];
        b2s[threadIdx.x] = b2[threadIdx.x];
    }
    __syncthreads();

    int lane = threadIdx.x & 63;
    int cq = lane & 7;
    int g = lane >> 3;
    int gw = blockIdx.x * 4 + (threadIdx.x >> 6);
    int nwaves = gridDim.x * 4;

    for (int node = gw; node < NN; node += nwaves) {
        int s0 = P[node * NSP1];
        int s1 = P[(node + 1) * NSP1];
        float4 sf = ((const float4*)x)[(size_t)node * 8 + cq];

        float ax0 = 0.f, ay0 = 0.f, az0 = 0.f, aw0 = 0.f;
        float ax1 = 0.f, ay1 = 0.f, az1 = 0.f, aw1 = 0.f;
        int e = s0;
        for (; e + 15 < s1; e += 16) {
            int c0 = col[e + g];
            int c1 = col[e + 8 + g];
            float2 f0 = x16f2[(size_t)c0 * 8 + cq];
            float2 f1 = x16f2[(size_t)c1 * 8 + cq];
            h4acc(f0, ax0, ay0, az0, aw0);
            h4acc(f1, ax1, ay1, az1, aw1);
        }
        for (int ee = e + g; ee < s1; ee += 8) {
            float2 f = x16f2[(size_t)col[ee] * 8 + cq];
            h4acc(f, ax0, ay0, az0, aw0);
        }
        float avx = ax0 + ax1, avy = ay0 + ay1, avz = az0 + az1, avw = aw0 + aw1;
        avx += __shfl_xor(avx, 8);  avy += __shfl_xor(avy, 8);
        avz += __shfl_xor(avz, 8);  avw += __shfl_xor(avw, 8);
        avx += __shfl_xor(avx, 16); avy += __shfl_xor(avy, 16);
        avz += __shfl_xor(avz, 16); avw += __shfl_xor(avw, 16);
        avx += __shfl_xor(avx, 32); avy += __shfl_xor(avy, 32);
        avz += __shfl_xor(avz, 32); avw += __shfl_xor(avw, 32);
        avx += sf.x; avy += sf.y; avz += sf.z; avw += sf.w;

        // pack aggregate pairs: u0 = (ch 4cq, 4cq+1), u1 = (ch 4cq+2, 4cq+3)
        unsigned u0 = pkh2(avx, avy);
        unsigned u1 = pkh2(avz, avw);

        // layer A: pair p -> broadcast lane p>>1; even p in u0, odd in u1
        float sa = b1s[lane], sb = 0.f;
#pragma unroll
        for (int i = 0; i < 8; ++i) {
            sa = fdot2u(rdlaneu(u0, i), W1s[(2 * i) * 64 + lane],     sa);
            sb = fdot2u(rdlaneu(u1, i), W1s[(2 * i + 1) * 64 + lane], sb);
        }
        float t = fmaxf(sa + sb, 0.f);

        // pack t pairs: lane j holds pair j>>1 = (t_{j&~1}, t_{j|1})
        float tt = __shfl_xor(t, 1);
        unsigned tp = pkh2((lane & 1) ? tt : t, (lane & 1) ? t : tt);

        float oa = b2s[lane], ob = 0.f;
#pragma unroll
        for (int q = 0; q < 32; q += 2) {
            oa = fdot2u(rdlaneu(tp, 2 * q),     W2s[q * 64 + lane],       oa);
            ob = fdot2u(rdlaneu(tp, 2 * q + 2), W2s[(q + 1) * 64 + lane], ob);
        }
        h16[(size_t)node * 64 + lane] = __float2half(fmaxf(oa + ob, 0.f));
    }
}

// ============ layer 2: half4 gather(h16) + dot2-MLP2 -> out ============
// gather frozen from R17: cq = lane&15, g = lane>>4.
__global__ __launch_bounds__(256) void fused2(const float2* __restrict__ hf2,
                                              const int* __restrict__ P,
                                              const int* __restrict__ col,
                                              const unsigned* __restrict__ W3p,
                                              const float* __restrict__ b3,
                                              const unsigned* __restrict__ W4p,
                                              const float* __restrict__ b4,
                                              float* __restrict__ out) {
    __shared__ unsigned W3s[32 * 64];   // 8 KB
    __shared__ unsigned W4s[32 * 32];   // 4 KB
    __shared__ float b3s[64];
    __shared__ float b4s[32];
    for (int i = threadIdx.x; i < 32 * 64; i += 256) W3s[i] = W3p[i];
    for (int i = threadIdx.x; i < 32 * 32; i += 256) W4s[i] = W4p[i];
    if (threadIdx.x < 64) b3s[threadIdx.x] = b3[threadIdx.x];
    if (threadIdx.x < 32) b4s[threadIdx.x] = b4[threadIdx.x];
    __syncthreads();

    int lane = threadIdx.x & 63;
    int cq = lane & 15;
    int g = lane >> 4;
    int gw = blockIdx.x * 4 + (threadIdx.x >> 6);
    int nwaves = gridDim.x * 4;

    for (int node = gw; node < NN; node += nwaves) {
        int s0 = P[node * NSP1];
        int s1 = P[(node + 1) * NSP1];
        float2 sfr = hf2[(size_t)node * 16 + cq];

        float ax0 = 0.f, ay0 = 0.f, az0 = 0.f, aw0 = 0.f;
        float ax1 = 0.f, ay1 = 0.f, az1 = 0.f, aw1 = 0.f;
        float ax2 = 0.f, ay2 = 0.f, az2 = 0.f, aw2 = 0.f;
        float ax3 = 0.f, ay3 = 0.f, az3 = 0.f, aw3 = 0.f;
        int e = s0;
        for (; e + 15 < s1; e += 16) {
            int c0 = col[e + g];
            int c1 = col[e + 4 + g];
            int c2 = col[e + 8 + g];
            int c3 = col[e + 12 + g];
            float2 f0 = hf2[(size_t)c0 * 16 + cq];
            float2 f1 = hf2[(size_t)c1 * 16 + cq];
            float2 f2 = hf2[(size_t)c2 * 16 + cq];
            float2 f3 = hf2[(size_t)c3 * 16 + cq];
            h4acc(f0, ax0, ay0, az0, aw0);
            h4acc(f1, ax1, ay1, az1, aw1);
            h4acc(f2, ax2, ay2, az2, aw2);
            h4acc(f3, ax3, ay3, az3, aw3);
        }
        for (int ee = e + g; ee < s1; ee += 4) {
            float2 f = hf2[(size_t)col[ee] * 16 + cq];
            h4acc(f, ax0, ay0, az0, aw0);
        }
        float avx = (ax0 + ax1) + (ax2 + ax3);
        float avy = (ay0 + ay1) + (ay2 + ay3);
        float avz = (az0 + az1) + (az2 + az3);
        float avw = (aw0 + aw1) + (aw2 + aw3);
        avx += __shfl_xor(avx, 16); avy += __shfl_xor(avy, 16);
        avz += __shfl_xor(avz, 16); avw += __shfl_xor(avw, 16);
        avx += __shfl_xor(avx, 32); avy += __shfl_xor(avy, 32);
        avz += __shfl_xor(avz, 32); avw += __shfl_xor(avw, 32);
        {
            __half2 lo = *reinterpret_cast<__half2*>(&sfr.x);
            __half2 hi = *reinterpret_cast<__half2*>(&sfr.y);
            float2 a = __half22float2(lo), b = __half22float2(hi);
            avx += a.x; avy += a.y; avz += b.x; avw += b.y;
        }

        unsigned u0 = pkh2(avx, avy);
        unsigned u1 = pkh2(avz, avw);

        // layer A: 32 pairs; pair p -> broadcast lane p>>1
        float sa = b3s[lane], sb = 0.f;
#pragma unroll
        for (int i = 0; i < 16; ++i) {
            sa = fdot2u(rdlaneu(u0, i), W3s[(2 * i) * 64 + lane],     sa);
            sb = fdot2u(rdlaneu(u1, i), W3s[(2 * i + 1) * 64 + lane], sb);
        }
        float t = fmaxf(sa + sb, 0.f);

        float tt = __shfl_xor(t, 1);
        unsigned tp = pkh2((lane & 1) ? tt : t, (lane & 1) ? t : tt);

        float oa = b4s[lane & 31], ob = 0.f;
#pragma unroll
        for (int q = 0; q < 32; q += 2) {
            oa = fdot2u(rdlaneu(tp, 2 * q),     W4s[q * 32 + (lane & 31)],       oa);
            ob = fdot2u(rdlaneu(tp, 2 * q + 2), W4s[(q + 1) * 32 + (lane & 31)], ob);
        }
        if (lane < 32) out[(size_t)node * 32 + lane] = oa + ob;
    }
}

extern "C" void kernel_launch(void* const* d_in, const int* in_sizes, int n_in,
                              void* d_out, int out_size, void* d_ws, size_t ws_size,
                              hipStream_t stream) {
    const float* x  = (const float*)d_in[0];
    const int*   ei = (const int*)d_in[1];
    const float* W1 = (const float*)d_in[2];
    const float* b1 = (const float*)d_in[3];
    const float* W2 = (const float*)d_in[4];
    const float* b2 = (const float*)d_in[5];
    const float* W3 = (const float*)d_in[6];
    const float* b3 = (const float*)d_in[7];
    const float* W4 = (const float*)d_in[8];
    const float* b4 = (const float*)d_in[9];
    float* out = (float*)d_out;

    char* ws = (char*)d_ws;
    __half* h16   = (__half*)ws;                      ws += (size_t)NN * 64 * 2;           // 12.8 MB
    __half* x16   = (__half*)ws;                      ws += (size_t)NN * 32 * 2;           // 6.4 MB
    int*   col    = (int*)ws;                         ws += (size_t)NE * 4;                // 6.4 MB
    int*   P      = (int*)ws;                         ws += (size_t)(NN * NSP1 + 1) * 4;   // 5.6 MB
    int*   deg2   = (int*)ws;                         ws += (size_t)NN * NS * 4;           // 5.2 MB
    int*   segbuf = (int*)ws;                         ws += (size_t)NE * 4;                // 6.4 MB
    int* scanned  = (int*)ws;                         ws += (size_t)NN * 4;
    int*   bsums  = (int*)ws;                         ws += (size_t)NB * 4;
    int*  segcnt  = (int*)ws;                         ws += (size_t)NSEG * 4;
    int* segstart = (int*)ws;                         ws += (size_t)(NSEG + 1) * 4;
    int* cursorA  = (int*)ws;                         ws += (size_t)NSEG * 4;
    unsigned* W1p = (unsigned*)ws;                    ws += (size_t)16 * 64 * 4;
    unsigned* W2p = (unsigned*)ws;                    ws += (size_t)32 * 64 * 4;
    unsigned* W3p = (unsigned*)ws;                    ws += (size_t)32 * 64 * 4;
    unsigned* W4p = (unsigned*)ws;                    ws += (size_t)32 * 32 * 4;

    // ---- build: two-phase LDS-staged radix + packing ----
    (void)hipMemsetAsync(segcnt, 0, (size_t)NSEG * 4, stream);
    cvt_k<<<(NN * 16 + 255) / 256, 256, 0, stream>>>((const float2*)x, (__half2*)x16);
    packw_k<<<8, 256, 0, stream>>>(W1, W2, W3, W4, W1p, W2p, W3p, W4p);
    seghist_k<<<GRID_E, 256, 0, stream>>>(ei, segcnt);
    segscan_k<<<1, 512, 0, stream>>>(segcnt, segstart, cursorA);
    fillA_k<<<GRID_E, 256, 0, stream>>>(ei, cursorA, segbuf);
    deghist_k<<<NSEG, 256, 0, stream>>>(segbuf, segstart, deg2);
    scan1_k<<<NB, 256, 0, stream>>>(deg2, scanned, bsums);
    scan2_k<<<1, 512, 0, stream>>>(bsums);
    scan3b_k<<<NB, 256, 0, stream>>>(scanned, bsums, deg2, P);
    fillB_k<<<NSEG, 256, 0, stream>>>(segbuf, segstart, P, col);

    // ---- fused layers: dot2 MLP ----
    fused1<<<1536, 256, 0, stream>>>(x, (const float2*)x16, P, col,
                                     W1p, b1, W2p, b2, h16);
    fused2<<<1536, 256, 0, stream>>>((const float2*)h16, P, col,
                                     W3p, b3, W4p, b4, out);
}

// Round 21
// 241.047 us; speedup vs baseline: 1.3456x; 1.0984x over previous
//
#include <hip/hip_runtime.h>
#include <hip/hip_fp16.h>

#define NN 100000
#define NE 1600000
#define NB 391        // ceil(NN/256)
#define NS 13         // src slices: slice = src >> 13
#define NSP1 14
#define SLICE_SHIFT 13
#define NSEG 391      // dst segments of 256 nodes: seg = dst >> 8
#define EPB 4096      // edges per fillA/seghist block
#define GRID_E 391    // ceil(NE/EPB)

typedef _Float16 h2_t __attribute__((ext_vector_type(2)));

__device__ __forceinline__ unsigned pkh2(float lo, float hi) {
    auto v = __builtin_amdgcn_cvt_pkrtz(lo, hi);   // __fp16 ext_vector(2)
    unsigned u; __builtin_memcpy(&u, &v, 4); return u;
}
__device__ __forceinline__ float fdot2u(unsigned a, unsigned b, float c) {
    h2_t x, y; __builtin_memcpy(&x, &a, 4); __builtin_memcpy(&y, &b, 4);
    return __builtin_amdgcn_fdot2(x, y, c, false);
}
__device__ __forceinline__ unsigned rdlaneu(unsigned v, int i) {
    return (unsigned)__builtin_amdgcn_readlane((int)v, i);
}

__device__ __forceinline__ void h4acc(float2 raw, float& ax, float& ay, float& az, float& aw) {
    __half2 lo = *reinterpret_cast<__half2*>(&raw.x);
    __half2 hi = *reinterpret_cast<__half2*>(&raw.y);
    float2 a = __half22float2(lo);
    float2 b = __half22float2(hi);
    ax += a.x; ay += a.y; az += b.x; aw += b.y;
}

// ===================== build phase A: segment sort (frozen) =====================

__global__ __launch_bounds__(256) void seghist_k(const int* __restrict__ ei,
                                                 int* __restrict__ segcnt) {
    __shared__ int cnt[NSEG];
    for (int i = threadIdx.x; i < NSEG; i += 256) cnt[i] = 0;
    __syncthreads();
    int eb = blockIdx.x * EPB;
    int ee = (eb + EPB < NE) ? eb + EPB : NE;
    for (int e = eb + threadIdx.x; e < ee; e += 256)
        atomicAdd(&cnt[ei[NE + e] >> 8], 1);
    __syncthreads();
    for (int i = threadIdx.x; i < NSEG; i += 256)
        if (cnt[i]) atomicAdd(&segcnt[i], cnt[i]);
}

__global__ __launch_bounds__(512) void segscan_k(const int* __restrict__ segcnt,
                                                 int* __restrict__ segstart,
                                                 int* __restrict__ cursorA) {
    __shared__ int tmp[512];
    int t = threadIdx.x;
    int v = (t < NSEG) ? segcnt[t] : 0;
    tmp[t] = v;
    __syncthreads();
#pragma unroll
    for (int off = 1; off < 512; off <<= 1) {
        int u = (t >= off) ? tmp[t - off] : 0;
        __syncthreads();
        tmp[t] += u;
        __syncthreads();
    }
    if (t < NSEG) {
        int excl = tmp[t] - v;
        segstart[t] = excl;
        cursorA[t] = excl;
    }
    if (t == 0) segstart[NSEG] = NE;
}

__global__ __launch_bounds__(256) void fillA_k(const int* __restrict__ ei,
                                               int* __restrict__ cursorA,
                                               int* __restrict__ segbuf) {
    __shared__ int cnt[NSEG];
    __shared__ int base[NSEG];
    for (int i = threadIdx.x; i < NSEG; i += 256) cnt[i] = 0;
    __syncthreads();

    int eb = blockIdx.x * EPB;
    int pay[16], sb[16];
#pragma unroll
    for (int k = 0; k < 16; ++k) {
        int e = eb + k * 256 + threadIdx.x;
        sb[k] = -1;
        pay[k] = 0;
        if (e < NE) {
            int src = ei[e];
            int dst = ei[NE + e];
            int seg = dst >> 8;
            int off = atomicAdd(&cnt[seg], 1);
            pay[k] = ((dst & 255) << 17) | src;
            sb[k] = (seg << 12) | off;
        }
    }
    __syncthreads();
    for (int b = threadIdx.x; b < NSEG; b += 256)
        base[b] = cnt[b] ? atomicAdd(&cursorA[b], cnt[b]) : 0;
    __syncthreads();
#pragma unroll
    for (int k = 0; k < 16; ++k) {
        if (sb[k] >= 0) {
            int seg = sb[k] >> 12;
            int off = sb[k] & 4095;
            segbuf[base[seg] + off] = pay[k];
        }
    }
}

// ===================== build phase B (frozen) =====================

__global__ __launch_bounds__(256) void deghist_k(const int* __restrict__ segbuf,
                                                 const int* __restrict__ segstart,
                                                 int* __restrict__ deg2) {
    __shared__ int cnt[256 * NS];
    for (int i = threadIdx.x; i < 256 * NS; i += 256) cnt[i] = 0;
    __syncthreads();
    int s0 = segstart[blockIdx.x], s1 = segstart[blockIdx.x + 1];
    for (int e = s0 + threadIdx.x; e < s1; e += 256) {
        int pk = segbuf[e];
        int l = pk >> 17;
        int src = pk & 0x1FFFF;
        atomicAdd(&cnt[l * NS + (src >> SLICE_SHIFT)], 1);
    }
    __syncthreads();
    int n = blockIdx.x * 256 + threadIdx.x;
    if (n < NN) {
#pragma unroll
        for (int s = 0; s < NS; ++s)
            deg2[n * NS + s] = cnt[threadIdx.x * NS + s];
    }
}

__global__ __launch_bounds__(256) void scan1_k(const int* __restrict__ deg2,
                                               int* __restrict__ scanned,
                                               int* __restrict__ bsums) {
    __shared__ int tmp[256];
    int i = blockIdx.x * 256 + threadIdx.x;
    int v = 0;
    if (i < NN) {
#pragma unroll
        for (int k = 0; k < NS; ++k) v += deg2[i * NS + k];
    }
    tmp[threadIdx.x] = v;
    __syncthreads();
#pragma unroll
    for (int off = 1; off < 256; off <<= 1) {
        int t = (threadIdx.x >= off) ? tmp[threadIdx.x - off] : 0;
        __syncthreads();
        tmp[threadIdx.x] += t;
        __syncthreads();
    }
    if (i < NN) scanned[i] = tmp[threadIdx.x];
    if (threadIdx.x == 255) bsums[blockIdx.x] = tmp[255];
}

__global__ __launch_bounds__(512) void scan2_k(int* __restrict__ bsums) {
    __shared__ int tmp[512];
    int v = (threadIdx.x < NB) ? bsums[threadIdx.x] : 0;
    tmp[threadIdx.x] = v;
    __syncthreads();
#pragma unroll
    for (int off = 1; off < 512; off <<= 1) {
        int t = (threadIdx.x >= off) ? tmp[threadIdx.x - off] : 0;
        __syncthreads();
        tmp[threadIdx.x] += t;
        __syncthreads();
    }
    if (threadIdx.x < NB) bsums[threadIdx.x] = tmp[threadIdx.x];
}

__global__ __launch_bounds__(256) void scan3b_k(const int* __restrict__ scanned,
                                                const int* __restrict__ bsums,
                                                const int* __restrict__ deg2,
                                                int* __restrict__ P) {
    int i = blockIdx.x * 256 + threadIdx.x;
    if (i < NN) {
        int d = 0;
#pragma unroll
        for (int k = 0; k < NS; ++k) d += deg2[i * NS + k];
        int incl = scanned[i] + (blockIdx.x ? bsums[blockIdx.x - 1] : 0);
        int run = incl - d;
        P[i * NSP1 + 0] = run;
#pragma unroll
        for (int s = 0; s < NS; ++s) {
            P[i * NSP1 + s + 1] = run;
            run += deg2[i * NS + s];
        }
        if (i == NN - 1) P[NN * NSP1] = incl;   // sentinel = NE
    }
}

__global__ __launch_bounds__(256) void fillB_k(const int* __restrict__ segbuf,
                                               const int* __restrict__ segstart,
                                               const int* __restrict__ P,
                                               int* __restrict__ col) {
    __shared__ int cur[256 * NS];
    int n = blockIdx.x * 256 + threadIdx.x;
    if (n < NN) {
#pragma unroll
        for (int s = 0; s < NS; ++s)
            cur[threadIdx.x * NS + s] = P[n * NSP1 + s + 1];
    }
    __syncthreads();
    int s0 = segstart[blockIdx.x], s1 = segstart[blockIdx.x + 1];
    for (int e = s0 + threadIdx.x; e < s1; e += 256) {
        int pk = segbuf[e];
        int l = pk >> 17;
        int src = pk & 0x1FFFF;
        int pos = atomicAdd(&cur[l * NS + (src >> SLICE_SHIFT)], 1);
        col[pos] = src;
    }
}

__global__ __launch_bounds__(256) void cvt_k(const float2* __restrict__ x2,
                                             __half2* __restrict__ x16) {
    int i = blockIdx.x * 256 + threadIdx.x;
    if (i < NN * 16) {
        float2 v = x2[i];
        x16[i] = __floats2half2_rn(v.x, v.y);
    }
}

// pack weight pairs to half2: Wp[p][j] = (W[2p][j], W[2p+1][j])
__global__ __launch_bounds__(256) void packw_k(const float* __restrict__ W1,
                                               const float* __restrict__ W2,
                                               const float* __restrict__ W3,
                                               const float* __restrict__ W4,
                                               unsigned* __restrict__ W1p,
                                               unsigned* __restrict__ W2p,
                                               unsigned* __restrict__ W3p,
                                               unsigned* __restrict__ W4p) {
    int i = blockIdx.x * 256 + threadIdx.x;
    if (i < 16 * 64) {
        int p = i >> 6, j = i & 63;
        W1p[i] = pkh2(W1[(2 * p) * 64 + j], W1[(2 * p + 1) * 64 + j]);
    }
    if (i < 32 * 64) {
        int p = i >> 6, j = i & 63;
        W2p[i] = pkh2(W2[(2 * p) * 64 + j], W2[(2 * p + 1) * 64 + j]);
        W3p[i] = pkh2(W3[(2 * p) * 64 + j], W3[(2 * p + 1) * 64 + j]);
    }
    if (i < 32 * 32) {
        int p = i >> 5, j = i & 31;
        W4p[i] = pkh2(W4[(2 * p) * 32 + j], W4[(2 * p + 1) * 32 + j]);
    }
}

// ============ layer 1: half4 gather(x16) + dot2-MLP1 -> h16 ============
// gather frozen; + next-node P prefetch; grid 2048.
__global__ __launch_bounds__(256) void fused1(const float* __restrict__ x,
                                              const float2* __restrict__ x16f2,
                                              const int* __restrict__ P,
                                              const int* __restrict__ col,
                                              const unsigned* __restrict__ W1p,
                                              const float* __restrict__ b1,
                                              const unsigned* __restrict__ W2p,
                                              const float* __restrict__ b2,
                                              __half* __restrict__ h16) {
    __shared__ unsigned W1s[16 * 64];   // 4 KB
    __shared__ unsigned W2s[32 * 64];   // 8 KB
    __shared__ float b1s[64];
    __shared__ float b2s[64];
    for (int i = threadIdx.x; i < 16 * 64; i += 256) W1s[i] = W1p[i];
    for (int i = threadIdx.x; i < 32 * 64; i += 256) W2s[i] = W2p[i];
    if (threadIdx.x < 64) {
        b1s[threadIdx.x] = b1[threadIdx.x];
        b2s[threadIdx.x] = b2[threadIdx.x];
    }
    __syncthreads();

    int lane = threadIdx.x & 63;
    int cq = lane & 7;
    int g = lane >> 3;
    int gw = blockIdx.x * 4 + (threadIdx.x >> 6);
    int nwaves = gridDim.x * 4;

    int node = gw;
    int s0 = (node < NN) ? P[node * NSP1] : 0;
    int s1 = (node < NN) ? P[(node + 1) * NSP1] : 0;
    while (node < NN) {
        // prefetch next node's row bounds (in flight during gather+MLP)
        int nnode = node + nwaves;
        int s0n = (nnode < NN) ? P[nnode * NSP1] : 0;
        int s1n = (nnode < NN) ? P[(nnode + 1) * NSP1] : 0;

        float4 sf = ((const float4*)x)[(size_t)node * 8 + cq];

        float ax0 = 0.f, ay0 = 0.f, az0 = 0.f, aw0 = 0.f;
        float ax1 = 0.f, ay1 = 0.f, az1 = 0.f, aw1 = 0.f;
        int e = s0;
        for (; e + 15 < s1; e += 16) {
            int c0 = col[e + g];
            int c1 = col[e + 8 + g];
            float2 f0 = x16f2[(size_t)c0 * 8 + cq];
            float2 f1 = x16f2[(size_t)c1 * 8 + cq];
            h4acc(f0, ax0, ay0, az0, aw0);
            h4acc(f1, ax1, ay1, az1, aw1);
        }
        for (int ee = e + g; ee < s1; ee += 8) {
            float2 f = x16f2[(size_t)col[ee] * 8 + cq];
            h4acc(f, ax0, ay0, az0, aw0);
        }
        float avx = ax0 + ax1, avy = ay0 + ay1, avz = az0 + az1, avw = aw0 + aw1;
        avx += __shfl_xor(avx, 8);  avy += __shfl_xor(avy, 8);
        avz += __shfl_xor(avz, 8);  avw += __shfl_xor(avw, 8);
        avx += __shfl_xor(avx, 16); avy += __shfl_xor(avy, 16);
        avz += __shfl_xor(avz, 16); avw += __shfl_xor(avw, 16);
        avx += __shfl_xor(avx, 32); avy += __shfl_xor(avy, 32);
        avz += __shfl_xor(avz, 32); avw += __shfl_xor(avw, 32);
        avx += sf.x; avy += sf.y; avz += sf.z; avw += sf.w;

        unsigned u0 = pkh2(avx, avy);
        unsigned u1 = pkh2(avz, avw);

        float sa = b1s[lane], sb = 0.f;
#pragma unroll
        for (int i = 0; i < 8; ++i) {
            sa = fdot2u(rdlaneu(u0, i), W1s[(2 * i) * 64 + lane],     sa);
            sb = fdot2u(rdlaneu(u1, i), W1s[(2 * i + 1) * 64 + lane], sb);
        }
        float t = fmaxf(sa + sb, 0.f);

        float tt = __shfl_xor(t, 1);
        unsigned tp = pkh2((lane & 1) ? tt : t, (lane & 1) ? t : tt);

        float oa = b2s[lane], ob = 0.f;
#pragma unroll
        for (int q = 0; q < 32; q += 2) {
            oa = fdot2u(rdlaneu(tp, 2 * q),     W2s[q * 64 + lane],       oa);
            ob = fdot2u(rdlaneu(tp, 2 * q + 2), W2s[(q + 1) * 64 + lane], ob);
        }
        h16[(size_t)node * 64 + lane] = __float2half(fmaxf(oa + ob, 0.f));

        node = nnode; s0 = s0n; s1 = s1n;
    }
}

// ============ layer 2: half4 gather(h16) + dot2-MLP2 -> out ============
// gather frozen; + next-node P prefetch; grid 2048.
__global__ __launch_bounds__(256) void fused2(const float2* __restrict__ hf2,
                                              const int* __restrict__ P,
                                              const int* __restrict__ col,
                                              const unsigned* __restrict__ W3p,
                                              const float* __restrict__ b3,
                                              const unsigned* __restrict__ W4p,
                                              const float* __restrict__ b4,
                                              float* __restrict__ out) {
    __shared__ unsigned W3s[32 * 64];   // 8 KB
    __shared__ unsigned W4s[32 * 32];   // 4 KB
    __shared__ float b3s[64];
    __shared__ float b4s[32];
    for (int i = threadIdx.x; i < 32 * 64; i += 256) W3s[i] = W3p[i];
    for (int i = threadIdx.x; i < 32 * 32; i += 256) W4s[i] = W4p[i];
    if (threadIdx.x < 64) b3s[threadIdx.x] = b3[threadIdx.x];
    if (threadIdx.x < 32) b4s[threadIdx.x] = b4[threadIdx.x];
    __syncthreads();

    int lane = threadIdx.x & 63;
    int cq = lane & 15;
    int g = lane >> 4;
    int gw = blockIdx.x * 4 + (threadIdx.x >> 6);
    int nwaves = gridDim.x * 4;

    int node = gw;
    int s0 = (node < NN) ? P[node * NSP1] : 0;
    int s1 = (node < NN) ? P[(node + 1) * NSP1] : 0;
    while (node < NN) {
        int nnode = node + nwaves;
        int s0n = (nnode < NN) ? P[nnode * NSP1] : 0;
        int s1n = (nnode < NN) ? P[(nnode + 1) * NSP1] : 0;

        float2 sfr = hf2[(size_t)node * 16 + cq];

        float ax0 = 0.f, ay0 = 0.f, az0 = 0.f, aw0 = 0.f;
        float ax1 = 0.f, ay1 = 0.f, az1 = 0.f, aw1 = 0.f;
        float ax2 = 0.f, ay2 = 0.f, az2 = 0.f, aw2 = 0.f;
        float ax3 = 0.f, ay3 = 0.f, az3 = 0.f, aw3 = 0.f;
        int e = s0;
        for (; e + 15 < s1; e += 16) {
            int c0 = col[e + g];
            int c1 = col[e + 4 + g];
            int c2 = col[e + 8 + g];
            int c3 = col[e + 12 + g];
            float2 f0 = hf2[(size_t)c0 * 16 + cq];
            float2 f1 = hf2[(size_t)c1 * 16 + cq];
            float2 f2 = hf2[(size_t)c2 * 16 + cq];
            float2 f3 = hf2[(size_t)c3 * 16 + cq];
            h4acc(f0, ax0, ay0, az0, aw0);
            h4acc(f1, ax1, ay1, az1, aw1);
            h4acc(f2, ax2, ay2, az2, aw2);
            h4acc(f3, ax3, ay3, az3, aw3);
        }
        for (int ee = e + g; ee < s1; ee += 4) {
            float2 f = hf2[(size_t)col[ee] * 16 + cq];
            h4acc(f, ax0, ay0, az0, aw0);
        }
        float avx = (ax0 + ax1) + (ax2 + ax3);
        float avy = (ay0 + ay1) + (ay2 + ay3);
        float avz = (az0 + az1) + (az2 + az3);
        float avw = (aw0 + aw1) + (aw2 + aw3);
        avx += __shfl_xor(avx, 16); avy += __shfl_xor(avy, 16);
        avz += __shfl_xor(avz, 16); avw += __shfl_xor(avw, 16);
        avx += __shfl_xor(avx, 32); avy += __shfl_xor(avy, 32);
        avz += __shfl_xor(avz, 32); avw += __shfl_xor(avw, 32);
        {
            __half2 lo = *reinterpret_cast<__half2*>(&sfr.x);
            __half2 hi = *reinterpret_cast<__half2*>(&sfr.y);
            float2 a = __half22float2(lo), b = __half22float2(hi);
            avx += a.x; avy += a.y; avz += b.x; avw += b.y;
        }

        unsigned u0 = pkh2(avx, avy);
        unsigned u1 = pkh2(avz, avw);

        float sa = b3s[lane], sb = 0.f;
#pragma unroll
        for (int i = 0; i < 16; ++i) {
            sa = fdot2u(rdlaneu(u0, i), W3s[(2 * i) * 64 + lane],     sa);
            sb = fdot2u(rdlaneu(u1, i), W3s[(2 * i + 1) * 64 + lane], sb);
        }
        float t = fmaxf(sa + sb, 0.f);

        float tt = __shfl_xor(t, 1);
        unsigned tp = pkh2((lane & 1) ? tt : t, (lane & 1) ? t : tt);

        float oa = b4s[lane & 31], ob = 0.f;
#pragma unroll
        for (int q = 0; q < 32; q += 2) {
            oa = fdot2u(rdlaneu(tp, 2 * q),     W4s[q * 32 + (lane & 31)],       oa);
            ob = fdot2u(rdlaneu(tp, 2 * q + 2), W4s[(q + 1) * 32 + (lane & 31)], ob);
        }
        if (lane < 32) out[(size_t)node * 32 + lane] = oa + ob;

        node = nnode; s0 = s0n; s1 = s1n;
    }
}

extern "C" void kernel_launch(void* const* d_in, const int* in_sizes, int n_in,
                              void* d_out, int out_size, void* d_ws, size_t ws_size,
                              hipStream_t stream) {
    const float* x  = (const float*)d_in[0];
    const int*   ei = (const int*)d_in[1];
    const float* W1 = (const float*)d_in[2];
    const float* b1 = (const float*)d_in[3];
    const float* W2 = (const float*)d_in[4];
    const float* b2 = (const float*)d_in[5];
    const float* W3 = (const float*)d_in[6];
    const float* b3 = (const float*)d_in[7];
    const float* W4 = (const float*)d_in[8];
    const float* b4 = (const float*)d_in[9];
    float* out = (float*)d_out;

    char* ws = (char*)d_ws;
    __half* h16   = (__half*)ws;                      ws += (size_t)NN * 64 * 2;           // 12.8 MB
    __half* x16   = (__half*)ws;                      ws += (size_t)NN * 32 * 2;           // 6.4 MB
    int*   col    = (int*)ws;                         ws += (size_t)NE * 4;                // 6.4 MB
    int*   P      = (int*)ws;                         ws += (size_t)(NN * NSP1 + 1) * 4;   // 5.6 MB
    int*   deg2   = (int*)ws;                         ws += (size_t)NN * NS * 4;           // 5.2 MB
    int*   segbuf = (int*)ws;                         ws += (size_t)NE * 4;                // 6.4 MB
    int* scanned  = (int*)ws;                         ws += (size_t)NN * 4;
    int*   bsums  = (int*)ws;                         ws += (size_t)NB * 4;
    int*  segcnt  = (int*)ws;                         ws += (size_t)NSEG * 4;
    int* segstart = (int*)ws;                         ws += (size_t)(NSEG + 1) * 4;
    int* cursorA  = (int*)ws;                         ws += (size_t)NSEG * 4;
    unsigned* W1p = (unsigned*)ws;                    ws += (size_t)16 * 64 * 4;
    unsigned* W2p = (unsigned*)ws;                    ws += (size_t)32 * 64 * 4;
    unsigned* W3p = (unsigned*)ws;                    ws += (size_t)32 * 64 * 4;
    unsigned* W4p = (unsigned*)ws;                    ws += (size_t)32 * 32 * 4;

    // ---- build: two-phase LDS-staged radix + packing ----
    (void)hipMemsetAsync(segcnt, 0, (size_t)NSEG * 4, stream);
    cvt_k<<<(NN * 16 + 255) / 256, 256, 0, stream>>>((const float2*)x, (__half2*)x16);
    packw_k<<<8, 256, 0, stream>>>(W1, W2, W3, W4, W1p, W2p, W3p, W4p);
    seghist_k<<<GRID_E, 256, 0, stream>>>(ei, segcnt);
    segscan_k<<<1, 512, 0, stream>>>(segcnt, segstart, cursorA);
    fillA_k<<<GRID_E, 256, 0, stream>>>(ei, cursorA, segbuf);
    deghist_k<<<NSEG, 256, 0, stream>>>(segbuf, segstart, deg2);
    scan1_k<<<NB, 256, 0, stream>>>(deg2, scanned, bsums);
    scan2_k<<<1, 512, 0, stream>>>(bsums);
    scan3b_k<<<NB, 256, 0, stream>>>(scanned, bsums, deg2, P);
    fillB_k<<<NSEG, 256, 0, stream>>>(segbuf, segstart, P, col);

    // ---- fused layers: dot2 MLP, full occupancy (8 blocks/CU) ----
    fused1<<<2048, 256, 0, stream>>>(x, (const float2*)x16, P, col,
                                     W1p, b1, W2p, b2, h16);
    fused2<<<2048, 256, 0, stream>>>((const float2*)h16, P, col,
                                     W3p, b3, W4p, b4, out);
}

// Round 22
// 232.262 us; speedup vs baseline: 1.3965x; 1.0378x over previous
//
#include <hip/hip_runtime.h>
#include <hip/hip_fp16.h>

#define NN 100000
#define NE 1600000
#define NB 391        // ceil(NN/256)
#define NS 13         // src slices: slice = src >> 13
#define NSP1 14
#define SLICE_SHIFT 13
#define NSEG 391      // dst segments of 256 nodes: seg = dst >> 8
#define EPB 4096      // edges per fillA/seghist block
#define GRID_E 391    // ceil(NE/EPB)

typedef _Float16 h2_t __attribute__((ext_vector_type(2)));

__device__ __forceinline__ unsigned pkh2(float lo, float hi) {
    auto v = __builtin_amdgcn_cvt_pkrtz(lo, hi);   // __fp16 ext_vector(2)
    unsigned u; __builtin_memcpy(&u, &v, 4); return u;
}
__device__ __forceinline__ float fdot2u(unsigned a, unsigned b, float c) {
    h2_t x, y; __builtin_memcpy(&x, &a, 4); __builtin_memcpy(&y, &b, 4);
    return __builtin_amdgcn_fdot2(x, y, c, false);
}

__device__ __forceinline__ void h4acc(float2 raw, float& ax, float& ay, float& az, float& aw) {
    __half2 lo = *reinterpret_cast<__half2*>(&raw.x);
    __half2 hi = *reinterpret_cast<__half2*>(&raw.y);
    float2 a = __half22float2(lo);
    float2 b = __half22float2(hi);
    ax += a.x; ay += a.y; az += b.x; aw += b.y;
}

// ===================== build phase A: segment sort (frozen) =====================

__global__ __launch_bounds__(256) void seghist_k(const int* __restrict__ ei,
                                                 int* __restrict__ segcnt) {
    __shared__ int cnt[NSEG];
    for (int i = threadIdx.x; i < NSEG; i += 256) cnt[i] = 0;
    __syncthreads();
    int eb = blockIdx.x * EPB;
    int ee = (eb + EPB < NE) ? eb + EPB : NE;
    for (int e = eb + threadIdx.x; e < ee; e += 256)
        atomicAdd(&cnt[ei[NE + e] >> 8], 1);
    __syncthreads();
    for (int i = threadIdx.x; i < NSEG; i += 256)
        if (cnt[i]) atomicAdd(&segcnt[i], cnt[i]);
}

__global__ __launch_bounds__(512) void segscan_k(const int* __restrict__ segcnt,
                                                 int* __restrict__ segstart,
                                                 int* __restrict__ cursorA) {
    __shared__ int tmp[512];
    int t = threadIdx.x;
    int v = (t < NSEG) ? segcnt[t] : 0;
    tmp[t] = v;
    __syncthreads();
#pragma unroll
    for (int off = 1; off < 512; off <<= 1) {
        int u = (t >= off) ? tmp[t - off] : 0;
        __syncthreads();
        tmp[t] += u;
        __syncthreads();
    }
    if (t < NSEG) {
        int excl = tmp[t] - v;
        segstart[t] = excl;
        cursorA[t] = excl;
    }
    if (t == 0) segstart[NSEG] = NE;
}

__global__ __launch_bounds__(256) void fillA_k(const int* __restrict__ ei,
                                               int* __restrict__ cursorA,
                                               int* __restrict__ segbuf) {
    __shared__ int cnt[NSEG];
    __shared__ int base[NSEG];
    for (int i = threadIdx.x; i < NSEG; i += 256) cnt[i] = 0;
    __syncthreads();

    int eb = blockIdx.x * EPB;
    int pay[16], sb[16];
#pragma unroll
    for (int k = 0; k < 16; ++k) {
        int e = eb + k * 256 + threadIdx.x;
        sb[k] = -1;
        pay[k] = 0;
        if (e < NE) {
            int src = ei[e];
            int dst = ei[NE + e];
            int seg = dst >> 8;
            int off = atomicAdd(&cnt[seg], 1);
            pay[k] = ((dst & 255) << 17) | src;
            sb[k] = (seg << 12) | off;
        }
    }
    __syncthreads();
    for (int b = threadIdx.x; b < NSEG; b += 256)
        base[b] = cnt[b] ? atomicAdd(&cursorA[b], cnt[b]) : 0;
    __syncthreads();
#pragma unroll
    for (int k = 0; k < 16; ++k) {
        if (sb[k] >= 0) {
            int seg = sb[k] >> 12;
            int off = sb[k] & 4095;
            segbuf[base[seg] + off] = pay[k];
        }
    }
}

// ===================== build phase B (frozen) =====================

__global__ __launch_bounds__(256) void deghist_k(const int* __restrict__ segbuf,
                                                 const int* __restrict__ segstart,
                                                 int* __restrict__ deg2) {
    __shared__ int cnt[256 * NS];
    for (int i = threadIdx.x; i < 256 * NS; i += 256) cnt[i] = 0;
    __syncthreads();
    int s0 = segstart[blockIdx.x], s1 = segstart[blockIdx.x + 1];
    for (int e = s0 + threadIdx.x; e < s1; e += 256) {
        int pk = segbuf[e];
        int l = pk >> 17;
        int src = pk & 0x1FFFF;
        atomicAdd(&cnt[l * NS + (src >> SLICE_SHIFT)], 1);
    }
    __syncthreads();
    int n = blockIdx.x * 256 + threadIdx.x;
    if (n < NN) {
#pragma unroll
        for (int s = 0; s < NS; ++s)
            deg2[n * NS + s] = cnt[threadIdx.x * NS + s];
    }
}

__global__ __launch_bounds__(256) void scan1_k(const int* __restrict__ deg2,
                                               int* __restrict__ scanned,
                                               int* __restrict__ bsums) {
    __shared__ int tmp[256];
    int i = blockIdx.x * 256 + threadIdx.x;
    int v = 0;
    if (i < NN) {
#pragma unroll
        for (int k = 0; k < NS; ++k) v += deg2[i * NS + k];
    }
    tmp[threadIdx.x] = v;
    __syncthreads();
#pragma unroll
    for (int off = 1; off < 256; off <<= 1) {
        int t = (threadIdx.x >= off) ? tmp[threadIdx.x - off] : 0;
        __syncthreads();
        tmp[threadIdx.x] += t;
        __syncthreads();
    }
    if (i < NN) scanned[i] = tmp[threadIdx.x];
    if (threadIdx.x == 255) bsums[blockIdx.x] = tmp[255];
}

__global__ __launch_bounds__(512) void scan2_k(int* __restrict__ bsums) {
    __shared__ int tmp[512];
    int v = (threadIdx.x < NB) ? bsums[threadIdx.x] : 0;
    tmp[threadIdx.x] = v;
    __syncthreads();
#pragma unroll
    for (int off = 1; off < 512; off <<= 1) {
        int t = (threadIdx.x >= off) ? tmp[threadIdx.x - off] : 0;
        __syncthreads();
        tmp[threadIdx.x] += t;
        __syncthreads();
    }
    if (threadIdx.x < NB) bsums[threadIdx.x] = tmp[threadIdx.x];
}

__global__ __launch_bounds__(256) void scan3b_k(const int* __restrict__ scanned,
                                                const int* __restrict__ bsums,
                                                const int* __restrict__ deg2,
                                                int* __restrict__ P) {
    int i = blockIdx.x * 256 + threadIdx.x;
    if (i < NN) {
        int d = 0;
#pragma unroll
        for (int k = 0; k < NS; ++k) d += deg2[i * NS + k];
        int incl = scanned[i] + (blockIdx.x ? bsums[blockIdx.x - 1] : 0);
        int run = incl - d;
        P[i * NSP1 + 0] = run;
#pragma unroll
        for (int s = 0; s < NS; ++s) {
            P[i * NSP1 + s + 1] = run;
            run += deg2[i * NS + s];
        }
        if (i == NN - 1) P[NN * NSP1] = incl;   // sentinel = NE
    }
}

__global__ __launch_bounds__(256) void fillB_k(const int* __restrict__ segbuf,
                                               const int* __restrict__ segstart,
                                               const int* __restrict__ P,
                                               int* __restrict__ col) {
    __shared__ int cur[256 * NS];
    int n = blockIdx.x * 256 + threadIdx.x;
    if (n < NN) {
#pragma unroll
        for (int s = 0; s < NS; ++s)
            cur[threadIdx.x * NS + s] = P[n * NSP1 + s + 1];
    }
    __syncthreads();
    int s0 = segstart[blockIdx.x], s1 = segstart[blockIdx.x + 1];
    for (int e = s0 + threadIdx.x; e < s1; e += 256) {
        int pk = segbuf[e];
        int l = pk >> 17;
        int src = pk & 0x1FFFF;
        int pos = atomicAdd(&cur[l * NS + (src >> SLICE_SHIFT)], 1);
        col[pos] = src;
    }
}

// merged: x -> fp16 conversion + weight pair-packing (one launch)
__global__ __launch_bounds__(256) void cvtpack_k(const float2* __restrict__ x2,
                                                 __half2* __restrict__ x16,
                                                 const float* __restrict__ W1,
                                                 const float* __restrict__ W2,
                                                 const float* __restrict__ W3,
                                                 const float* __restrict__ W4,
                                                 unsigned* __restrict__ W1p,
                                                 unsigned* __restrict__ W2p,
                                                 unsigned* __restrict__ W3p,
                                                 unsigned* __restrict__ W4p) {
    int i = blockIdx.x * 256 + threadIdx.x;
    if (i < NN * 16) {
        float2 v = x2[i];
        x16[i] = __floats2half2_rn(v.x, v.y);
    }
    if (i < 16 * 64) {
        int p = i >> 6, j = i & 63;
        W1p[i] = pkh2(W1[(2 * p) * 64 + j], W1[(2 * p + 1) * 64 + j]);
    }
    if (i < 32 * 64) {
        int p = i >> 6, j = i & 63;
        W2p[i] = pkh2(W2[(2 * p) * 64 + j], W2[(2 * p + 1) * 64 + j]);
        W3p[i] = pkh2(W3[(2 * p) * 64 + j], W3[(2 * p + 1) * 64 + j]);
    }
    if (i < 32 * 32) {
        int p = i >> 5, j = i & 31;
        W4p[i] = pkh2(W4[(2 * p) * 32 + j], W4[(2 * p + 1) * 32 + j]);
    }
}

// ============ layer 1: half4 gather(x16) + LDS-broadcast dot2-MLP1 -> h16 ============
__global__ __launch_bounds__(256) void fused1(const float* __restrict__ x,
                                              const float2* __restrict__ x16f2,
                                              const int* __restrict__ P,
                                              const int* __restrict__ col,
                                              const unsigned* __restrict__ W1p,
                                              const float* __restrict__ b1,
                                              const unsigned* __restrict__ W2p,
                                              const float* __restrict__ b2,
                                              __half* __restrict__ h16) {
    __shared__ unsigned W1s[16 * 64];   // 4 KB
    __shared__ unsigned W2s[32 * 64];   // 8 KB
    __shared__ float b1s[64];
    __shared__ float b2s[64];
    __shared__ unsigned aggL[4][16];    // per-wave aggregate pairs
    __shared__ unsigned tL[4][32];      // per-wave t pairs
    for (int i = threadIdx.x; i < 16 * 64; i += 256) W1s[i] = W1p[i];
    for (int i = threadIdx.x; i < 32 * 64; i += 256) W2s[i] = W2p[i];
    if (threadIdx.x < 64) {
        b1s[threadIdx.x] = b1[threadIdx.x];
        b2s[threadIdx.x] = b2[threadIdx.x];
    }
    __syncthreads();

    int lane = threadIdx.x & 63;
    int cq = lane & 7;
    int g = lane >> 3;
    int wv = threadIdx.x >> 6;
    int gw = blockIdx.x * 4 + wv;
    int nwaves = gridDim.x * 4;

    int node = gw;
    int s0 = (node < NN) ? P[node * NSP1] : 0;
    int s1 = (node < NN) ? P[(node + 1) * NSP1] : 0;
    while (node < NN) {
        int nnode = node + nwaves;
        int s0n = (nnode < NN) ? P[nnode * NSP1] : 0;
        int s1n = (nnode < NN) ? P[(nnode + 1) * NSP1] : 0;

        float4 sf = ((const float4*)x)[(size_t)node * 8 + cq];

        float ax0 = 0.f, ay0 = 0.f, az0 = 0.f, aw0 = 0.f;
        float ax1 = 0.f, ay1 = 0.f, az1 = 0.f, aw1 = 0.f;
        int e = s0;
        for (; e + 15 < s1; e += 16) {
            int c0 = col[e + g];
            int c1 = col[e + 8 + g];
            float2 f0 = x16f2[(size_t)c0 * 8 + cq];
            float2 f1 = x16f2[(size_t)c1 * 8 + cq];
            h4acc(f0, ax0, ay0, az0, aw0);
            h4acc(f1, ax1, ay1, az1, aw1);
        }
        for (int ee = e + g; ee < s1; ee += 8) {
            float2 f = x16f2[(size_t)col[ee] * 8 + cq];
            h4acc(f, ax0, ay0, az0, aw0);
        }
        float avx = ax0 + ax1, avy = ay0 + ay1, avz = az0 + az1, avw = aw0 + aw1;
        avx += __shfl_xor(avx, 8);  avy += __shfl_xor(avy, 8);
        avz += __shfl_xor(avz, 8);  avw += __shfl_xor(avw, 8);
        avx += __shfl_xor(avx, 16); avy += __shfl_xor(avy, 16);
        avz += __shfl_xor(avz, 16); avw += __shfl_xor(avw, 16);
        avx += __shfl_xor(avx, 32); avy += __shfl_xor(avy, 32);
        avz += __shfl_xor(avz, 32); avw += __shfl_xor(avw, 32);
        avx += sf.x; avy += sf.y; avz += sf.z; avw += sf.w;

        // stash aggregate pairs in wave-private LDS (lane<8 holds all 16 pairs)
        unsigned u0 = pkh2(avx, avy);
        unsigned u1 = pkh2(avz, avw);
        if (lane < 8)
            *reinterpret_cast<uint2*>(&aggL[wv][2 * cq]) = make_uint2(u0, u1);

        // layer A: broadcast pairs from LDS (uniform addr), weight per-lane
        float sa = b1s[lane], sb = 0.f;
#pragma unroll
        for (int i = 0; i < 8; ++i) {
            uint2 A = *reinterpret_cast<const uint2*>(&aggL[wv][2 * i]);
            sa = fdot2u(A.x, W1s[(2 * i) * 64 + lane],     sa);
            sb = fdot2u(A.y, W1s[(2 * i + 1) * 64 + lane], sb);
        }
        float t = fmaxf(sa + sb, 0.f);

        // stash t pairs: even lane j holds pair j>>1
        float tt = __shfl_xor(t, 1);
        unsigned tp = pkh2((lane & 1) ? tt : t, (lane & 1) ? t : tt);
        if (!(lane & 1)) tL[wv][lane >> 1] = tp;

        float oa = b2s[lane], ob = 0.f;
#pragma unroll
        for (int q = 0; q < 32; q += 2) {
            uint2 T = *reinterpret_cast<const uint2*>(&tL[wv][q]);
            oa = fdot2u(T.x, W2s[q * 64 + lane],       oa);
            ob = fdot2u(T.y, W2s[(q + 1) * 64 + lane], ob);
        }
        h16[(size_t)node * 64 + lane] = __float2half(fmaxf(oa + ob, 0.f));

        node = nnode; s0 = s0n; s1 = s1n;
    }
}

// ============ layer 2: half4 gather(h16) + LDS-broadcast dot2-MLP2 -> out ============
__global__ __launch_bounds__(256) void fused2(const float2* __restrict__ hf2,
                                              const int* __restrict__ P,
                                              const int* __restrict__ col,
                                              const unsigned* __restrict__ W3p,
                                              const float* __restrict__ b3,
                                              const unsigned* __restrict__ W4p,
                                              const float* __restrict__ b4,
                                              float* __restrict__ out) {
    __shared__ unsigned W3s[32 * 64];   // 8 KB
    __shared__ unsigned W4s[32 * 32];   // 4 KB
    __shared__ float b3s[64];
    __shared__ float b4s[32];
    __shared__ unsigned aggL[4][32];
    __shared__ unsigned tL[4][32];
    for (int i = threadIdx.x; i < 32 * 64; i += 256) W3s[i] = W3p[i];
    for (int i = threadIdx.x; i < 32 * 32; i += 256) W4s[i] = W4p[i];
    if (threadIdx.x < 64) b3s[threadIdx.x] = b3[threadIdx.x];
    if (threadIdx.x < 32) b4s[threadIdx.x] = b4[threadIdx.x];
    __syncthreads();

    int lane = threadIdx.x & 63;
    int cq = lane & 15;
    int g = lane >> 4;
    int wv = threadIdx.x >> 6;
    int gw = blockIdx.x * 4 + wv;
    int nwaves = gridDim.x * 4;

    int node = gw;
    int s0 = (node < NN) ? P[node * NSP1] : 0;
    int s1 = (node < NN) ? P[(node + 1) * NSP1] : 0;
    while (node < NN) {
        int nnode = node + nwaves;
        int s0n = (nnode < NN) ? P[nnode * NSP1] : 0;
        int s1n = (nnode < NN) ? P[(nnode + 1) * NSP1] : 0;

        float2 sfr = hf2[(size_t)node * 16 + cq];

        float ax0 = 0.f, ay0 = 0.f, az0 = 0.f, aw0 = 0.f;
        float ax1 = 0.f, ay1 = 0.f, az1 = 0.f, aw1 = 0.f;
        float ax2 = 0.f, ay2 = 0.f, az2 = 0.f, aw2 = 0.f;
        float ax3 = 0.f, ay3 = 0.f, az3 = 0.f, aw3 = 0.f;
        int e = s0;
        for (; e + 15 < s1; e += 16) {
            int c0 = col[e + g];
            int c1 = col[e + 4 + g];
            int c2 = col[e + 8 + g];
            int c3 = col[e + 12 + g];
            float2 f0 = hf2[(size_t)c0 * 16 + cq];
            float2 f1 = hf2[(size_t)c1 * 16 + cq];
            float2 f2 = hf2[(size_t)c2 * 16 + cq];
            float2 f3 = hf2[(size_t)c3 * 16 + cq];
            h4acc(f0, ax0, ay0, az0, aw0);
            h4acc(f1, ax1, ay1, az1, aw1);
            h4acc(f2, ax2, ay2, az2, aw2);
            h4acc(f3, ax3, ay3, az3, aw3);
        }
        for (int ee = e + g; ee < s1; ee += 4) {
            float2 f = hf2[(size_t)col[ee] * 16 + cq];
            h4acc(f, ax0, ay0, az0, aw0);
        }
        float avx = (ax0 + ax1) + (ax2 + ax3);
        float avy = (ay0 + ay1) + (ay2 + ay3);
        float avz = (az0 + az1) + (az2 + az3);
        float avw = (aw0 + aw1) + (aw2 + aw3);
        avx += __shfl_xor(avx, 16); avy += __shfl_xor(avy, 16);
        avz += __shfl_xor(avz, 16); avw += __shfl_xor(avw, 16);
        avx += __shfl_xor(avx, 32); avy += __shfl_xor(avy, 32);
        avz += __shfl_xor(avz, 32); avw += __shfl_xor(avw, 32);
        {
            __half2 lo = *reinterpret_cast<__half2*>(&sfr.x);
            __half2 hi = *reinterpret_cast<__half2*>(&sfr.y);
            float2 a = __half22float2(lo), b = __half22float2(hi);
            avx += a.x; avy += a.y; avz += b.x; avw += b.y;
        }

        unsigned u0 = pkh2(avx, avy);
        unsigned u1 = pkh2(avz, avw);
        if (lane < 16)
            *reinterpret_cast<uint2*>(&aggL[wv][2 * cq]) = make_uint2(u0, u1);

        float sa = b3s[lane], sb = 0.f;
#pragma unroll
        for (int i = 0; i < 16; ++i) {
            uint2 A = *reinterpret_cast<const uint2*>(&aggL[wv][2 * i]);
            sa = fdot2u(A.x, W3s[(2 * i) * 64 + lane],     sa);
            sb = fdot2u(A.y, W3s[(2 * i + 1) * 64 + lane], sb);
        }
        float t = fmaxf(sa + sb, 0.f);

        float tt = __shfl_xor(t, 1);
        unsigned tp = pkh2((lane & 1) ? tt : t, (lane & 1) ? t : tt);
        if (!(lane & 1)) tL[wv][lane >> 1] = tp;

        float oa = b4s[lane & 31], ob = 0.f;
#pragma unroll
        for (int q = 0; q < 32; q += 2) {
            uint2 T = *reinterpret_cast<const uint2*>(&tL[wv][q]);
            oa = fdot2u(T.x, W4s[q * 32 + (lane & 31)],       oa);
            ob = fdot2u(T.y, W4s[(q + 1) * 32 + (lane & 31)], ob);
        }
        if (lane < 32) out[(size_t)node * 32 + lane] = oa + ob;

        node = nnode; s0 = s0n; s1 = s1n;
    }
}

extern "C" void kernel_launch(void* const* d_in, const int* in_sizes, int n_in,
                              void* d_out, int out_size, void* d_ws, size_t ws_size,
                              hipStream_t stream) {
    const float* x  = (const float*)d_in[0];
    const int*   ei = (const int*)d_in[1];
    const float* W1 = (const float*)d_in[2];
    const float* b1 = (const float*)d_in[3];
    const float* W2 = (const float*)d_in[4];
    const float* b2 = (const float*)d_in[5];
    const float* W3 = (const float*)d_in[6];
    const float* b3 = (const float*)d_in[7];
    const float* W4 = (const float*)d_in[8];
    const float* b4 = (const float*)d_in[9];
    float* out = (float*)d_out;

    char* ws = (char*)d_ws;
    __half* h16   = (__half*)ws;                      ws += (size_t)NN * 64 * 2;           // 12.8 MB
    __half* x16   = (__half*)ws;                      ws += (size_t)NN * 32 * 2;           // 6.4 MB
    int*   col    = (int*)ws;                         ws += (size_t)NE * 4;                // 6.4 MB
    int*   P      = (int*)ws;                         ws += (size_t)(NN * NSP1 + 1) * 4;   // 5.6 MB
    int*   deg2   = (int*)ws;                         ws += (size_t)NN * NS * 4;           // 5.2 MB
    int*   segbuf = (int*)ws;                         ws += (size_t)NE * 4;                // 6.4 MB
    int* scanned  = (int*)ws;                         ws += (size_t)NN * 4;
    int*   bsums  = (int*)ws;                         ws += (size_t)NB * 4;
    int*  segcnt  = (int*)ws;                         ws += (size_t)NSEG * 4;
    int* segstart = (int*)ws;                         ws += (size_t)(NSEG + 1) * 4;
    int* cursorA  = (int*)ws;                         ws += (size_t)NSEG * 4;
    unsigned* W1p = (unsigned*)ws;                    ws += (size_t)16 * 64 * 4;
    unsigned* W2p = (unsigned*)ws;                    ws += (size_t)32 * 64 * 4;
    unsigned* W3p = (unsigned*)ws;                    ws += (size_t)32 * 64 * 4;
    unsigned* W4p = (unsigned*)ws;                    ws += (size_t)32 * 32 * 4;

    // ---- build: two-phase LDS-staged radix + merged cvt/pack ----
    (void)hipMemsetAsync(segcnt, 0, (size_t)NSEG * 4, stream);
    cvtpack_k<<<(NN * 16 + 255) / 256, 256, 0, stream>>>((const float2*)x, (__half2*)x16,
                                                         W1, W2, W3, W4, W1p, W2p, W3p, W4p);
    seghist_k<<<GRID_E, 256, 0, stream>>>(ei, segcnt);
    segscan_k<<<1, 512, 0, stream>>>(segcnt, segstart, cursorA);
    fillA_k<<<GRID_E, 256, 0, stream>>>(ei, cursorA, segbuf);
    deghist_k<<<NSEG, 256, 0, stream>>>(segbuf, segstart, deg2);
    scan1_k<<<NB, 256, 0, stream>>>(deg2, scanned, bsums);
    scan2_k<<<1, 512, 0, stream>>>(bsums);
    scan3b_k<<<NB, 256, 0, stream>>>(scanned, bsums, deg2, P);
    fillB_k<<<NSEG, 256, 0, stream>>>(segbuf, segstart, P, col);

    // ---- fused layers: LDS-broadcast dot2 MLP, 8 blocks/CU ----
    fused1<<<2048, 256, 0, stream>>>(x, (const float2*)x16, P, col,
                                     W1p, b1, W2p, b2, h16);
    fused2<<<2048, 256, 0, stream>>>((const float2*)h16, P, col,
                                     W3p, b3, W4p, b4, out);
}

// Round 23
// 225.916 us; speedup vs baseline: 1.4357x; 1.0281x over previous
//
#include <hip/hip_runtime.h>
#include <hip/hip_fp16.h>

#define NN 100000
#define NE 1600000
#define NB 391        // ceil(NN/256)
#define NS 7          // src slices: slice = src >> 14 (16384 nodes/slice, 2MB fp16 @64ch)
#define NSP1 8
#define SLICE_SHIFT 14
#define NSEG 391      // dst segments of 256 nodes: seg = dst >> 8
#define EPB 4096      // edges per fillA/seghist block
#define GRID_E 391    // ceil(NE/EPB)

typedef _Float16 h2_t __attribute__((ext_vector_type(2)));

__device__ __forceinline__ unsigned pkh2(float lo, float hi) {
    auto v = __builtin_amdgcn_cvt_pkrtz(lo, hi);   // __fp16 ext_vector(2)
    unsigned u; __builtin_memcpy(&u, &v, 4); return u;
}
__device__ __forceinline__ float fdot2u(unsigned a, unsigned b, float c) {
    h2_t x, y; __builtin_memcpy(&x, &a, 4); __builtin_memcpy(&y, &b, 4);
    return __builtin_amdgcn_fdot2(x, y, c, false);
}

__device__ __forceinline__ void h4acc(float2 raw, float& ax, float& ay, float& az, float& aw) {
    __half2 lo = *reinterpret_cast<__half2*>(&raw.x);
    __half2 hi = *reinterpret_cast<__half2*>(&raw.y);
    float2 a = __half22float2(lo);
    float2 b = __half22float2(hi);
    ax += a.x; ay += a.y; az += b.x; aw += b.y;
}

// ===================== build phase A: segment sort (frozen) =====================

__global__ __launch_bounds__(256) void seghist_k(const int* __restrict__ ei,
                                                 int* __restrict__ segcnt) {
    __shared__ int cnt[NSEG];
    for (int i = threadIdx.x; i < NSEG; i += 256) cnt[i] = 0;
    __syncthreads();
    int eb = blockIdx.x * EPB;
    int ee = (eb + EPB < NE) ? eb + EPB : NE;
    for (int e = eb + threadIdx.x; e < ee; e += 256)
        atomicAdd(&cnt[ei[NE + e] >> 8], 1);
    __syncthreads();
    for (int i = threadIdx.x; i < NSEG; i += 256)
        if (cnt[i]) atomicAdd(&segcnt[i], cnt[i]);
}

__global__ __launch_bounds__(512) void segscan_k(const int* __restrict__ segcnt,
                                                 int* __restrict__ segstart,
                                                 int* __restrict__ cursorA) {
    __shared__ int tmp[512];
    int t = threadIdx.x;
    int v = (t < NSEG) ? segcnt[t] : 0;
    tmp[t] = v;
    __syncthreads();
#pragma unroll
    for (int off = 1; off < 512; off <<= 1) {
        int u = (t >= off) ? tmp[t - off] : 0;
        __syncthreads();
        tmp[t] += u;
        __syncthreads();
    }
    if (t < NSEG) {
        int excl = tmp[t] - v;
        segstart[t] = excl;
        cursorA[t] = excl;
    }
    if (t == 0) segstart[NSEG] = NE;
}

__global__ __launch_bounds__(256) void fillA_k(const int* __restrict__ ei,
                                               int* __restrict__ cursorA,
                                               int* __restrict__ segbuf) {
    __shared__ int cnt[NSEG];
    __shared__ int base[NSEG];
    for (int i = threadIdx.x; i < NSEG; i += 256) cnt[i] = 0;
    __syncthreads();

    int eb = blockIdx.x * EPB;
    int pay[16], sb[16];
#pragma unroll
    for (int k = 0; k < 16; ++k) {
        int e = eb + k * 256 + threadIdx.x;
        sb[k] = -1;
        pay[k] = 0;
        if (e < NE) {
            int src = ei[e];
            int dst = ei[NE + e];
            int seg = dst >> 8;
            int off = atomicAdd(&cnt[seg], 1);
            pay[k] = ((dst & 255) << 17) | src;
            sb[k] = (seg << 12) | off;
        }
    }
    __syncthreads();
    for (int b = threadIdx.x; b < NSEG; b += 256)
        base[b] = cnt[b] ? atomicAdd(&cursorA[b], cnt[b]) : 0;
    __syncthreads();
#pragma unroll
    for (int k = 0; k < 16; ++k) {
        if (sb[k] >= 0) {
            int seg = sb[k] >> 12;
            int off = sb[k] & 4095;
            segbuf[base[seg] + off] = pay[k];
        }
    }
}

// ===================== build phase B (NS = 7) =====================

__global__ __launch_bounds__(256) void deghist_k(const int* __restrict__ segbuf,
                                                 const int* __restrict__ segstart,
                                                 int* __restrict__ deg2) {
    __shared__ int cnt[256 * NS];   // 7 KB
    for (int i = threadIdx.x; i < 256 * NS; i += 256) cnt[i] = 0;
    __syncthreads();
    int s0 = segstart[blockIdx.x], s1 = segstart[blockIdx.x + 1];
    for (int e = s0 + threadIdx.x; e < s1; e += 256) {
        int pk = segbuf[e];
        int l = pk >> 17;
        int src = pk & 0x1FFFF;
        atomicAdd(&cnt[l * NS + (src >> SLICE_SHIFT)], 1);
    }
    __syncthreads();
    int n = blockIdx.x * 256 + threadIdx.x;
    if (n < NN) {
#pragma unroll
        for (int s = 0; s < NS; ++s)
            deg2[n * NS + s] = cnt[threadIdx.x * NS + s];
    }
}

__global__ __launch_bounds__(256) void scan1_k(const int* __restrict__ deg2,
                                               int* __restrict__ scanned,
                                               int* __restrict__ bsums) {
    __shared__ int tmp[256];
    int i = blockIdx.x * 256 + threadIdx.x;
    int v = 0;
    if (i < NN) {
#pragma unroll
        for (int k = 0; k < NS; ++k) v += deg2[i * NS + k];
    }
    tmp[threadIdx.x] = v;
    __syncthreads();
#pragma unroll
    for (int off = 1; off < 256; off <<= 1) {
        int t = (threadIdx.x >= off) ? tmp[threadIdx.x - off] : 0;
        __syncthreads();
        tmp[threadIdx.x] += t;
        __syncthreads();
    }
    if (i < NN) scanned[i] = tmp[threadIdx.x];
    if (threadIdx.x == 255) bsums[blockIdx.x] = tmp[255];
}

__global__ __launch_bounds__(512) void scan2_k(int* __restrict__ bsums) {
    __shared__ int tmp[512];
    int v = (threadIdx.x < NB) ? bsums[threadIdx.x] : 0;
    tmp[threadIdx.x] = v;
    __syncthreads();
#pragma unroll
    for (int off = 1; off < 512; off <<= 1) {
        int t = (threadIdx.x >= off) ? tmp[threadIdx.x - off] : 0;
        __syncthreads();
        tmp[threadIdx.x] += t;
        __syncthreads();
    }
    if (threadIdx.x < NB) bsums[threadIdx.x] = tmp[threadIdx.x];
}

__global__ __launch_bounds__(256) void scan3b_k(const int* __restrict__ scanned,
                                                const int* __restrict__ bsums,
                                                const int* __restrict__ deg2,
                                                int* __restrict__ P) {
    int i = blockIdx.x * 256 + threadIdx.x;
    if (i < NN) {
        int d = 0;
#pragma unroll
        for (int k = 0; k < NS; ++k) d += deg2[i * NS + k];
        int incl = scanned[i] + (blockIdx.x ? bsums[blockIdx.x - 1] : 0);
        int run = incl - d;
        P[i * NSP1 + 0] = run;
#pragma unroll
        for (int s = 0; s < NS; ++s) {
            P[i * NSP1 + s + 1] = run;
            run += deg2[i * NS + s];
        }
        if (i == NN - 1) P[NN * NSP1] = incl;   // sentinel = NE
    }
}

__global__ __launch_bounds__(256) void fillB_k(const int* __restrict__ segbuf,
                                               const int* __restrict__ segstart,
                                               const int* __restrict__ P,
                                               int* __restrict__ col) {
    __shared__ int cur[256 * NS];   // 7 KB
    int n = blockIdx.x * 256 + threadIdx.x;
    if (n < NN) {
#pragma unroll
        for (int s = 0; s < NS; ++s)
            cur[threadIdx.x * NS + s] = P[n * NSP1 + s + 1];
    }
    __syncthreads();
    int s0 = segstart[blockIdx.x], s1 = segstart[blockIdx.x + 1];
    for (int e = s0 + threadIdx.x; e < s1; e += 256) {
        int pk = segbuf[e];
        int l = pk >> 17;
        int src = pk & 0x1FFFF;
        int pos = atomicAdd(&cur[l * NS + (src >> SLICE_SHIFT)], 1);
        col[pos] = src;
    }
}

// merged: x -> fp16 conversion + weight pair-packing (one launch)
__global__ __launch_bounds__(256) void cvtpack_k(const float2* __restrict__ x2,
                                                 __half2* __restrict__ x16,
                                                 const float* __restrict__ W1,
                                                 const float* __restrict__ W2,
                                                 const float* __restrict__ W3,
                                                 const float* __restrict__ W4,
                                                 unsigned* __restrict__ W1p,
                                                 unsigned* __restrict__ W2p,
                                                 unsigned* __restrict__ W3p,
                                                 unsigned* __restrict__ W4p) {
    int i = blockIdx.x * 256 + threadIdx.x;
    if (i < NN * 16) {
        float2 v = x2[i];
        x16[i] = __floats2half2_rn(v.x, v.y);
    }
    if (i < 16 * 64) {
        int p = i >> 6, j = i & 63;
        W1p[i] = pkh2(W1[(2 * p) * 64 + j], W1[(2 * p + 1) * 64 + j]);
    }
    if (i < 32 * 64) {
        int p = i >> 6, j = i & 63;
        W2p[i] = pkh2(W2[(2 * p) * 64 + j], W2[(2 * p + 1) * 64 + j]);
        W3p[i] = pkh2(W3[(2 * p) * 64 + j], W3[(2 * p + 1) * 64 + j]);
    }
    if (i < 32 * 32) {
        int p = i >> 5, j = i & 31;
        W4p[i] = pkh2(W4[(2 * p) * 32 + j], W4[(2 * p + 1) * 32 + j]);
    }
}

// ============ layer 1: half4 gather(x16) + LDS-broadcast dot2-MLP1 -> h16 ============
// + cross-node col prefetch (first 16-edge batch: 2 col loads)
__global__ __launch_bounds__(256) void fused1(const float* __restrict__ x,
                                              const float2* __restrict__ x16f2,
                                              const int* __restrict__ P,
                                              const int* __restrict__ col,
                                              const unsigned* __restrict__ W1p,
                                              const float* __restrict__ b1,
                                              const unsigned* __restrict__ W2p,
                                              const float* __restrict__ b2,
                                              __half* __restrict__ h16) {
    __shared__ unsigned W1s[16 * 64];   // 4 KB
    __shared__ unsigned W2s[32 * 64];   // 8 KB
    __shared__ float b1s[64];
    __shared__ float b2s[64];
    __shared__ unsigned aggL[4][16];
    __shared__ unsigned tL[4][32];
    for (int i = threadIdx.x; i < 16 * 64; i += 256) W1s[i] = W1p[i];
    for (int i = threadIdx.x; i < 32 * 64; i += 256) W2s[i] = W2p[i];
    if (threadIdx.x < 64) {
        b1s[threadIdx.x] = b1[threadIdx.x];
        b2s[threadIdx.x] = b2[threadIdx.x];
    }
    __syncthreads();

    int lane = threadIdx.x & 63;
    int cq = lane & 7;
    int g = lane >> 3;
    int wv = threadIdx.x >> 6;
    int gw = blockIdx.x * 4 + wv;
    int nwaves = gridDim.x * 4;

    int node = gw;
    int s0 = (node < NN) ? P[node * NSP1] : 0;
    int s1 = (node < NN) ? P[(node + 1) * NSP1] : 0;
    bool full = (node < NN) && (s0 + 15 < s1);
    int pc0 = 0, pc1 = 0;
    if (full) { pc0 = col[s0 + g]; pc1 = col[s0 + 8 + g]; }

    while (node < NN) {
        int nnode = node + nwaves;
        int s0n = (nnode < NN) ? P[nnode * NSP1] : 0;
        int s1n = (nnode < NN) ? P[(nnode + 1) * NSP1] : 0;
        bool fulln = (nnode < NN) && (s0n + 15 < s1n);
        int nc0 = 0, nc1 = 0;
        if (fulln) { nc0 = col[s0n + g]; nc1 = col[s0n + 8 + g]; }

        float4 sf = ((const float4*)x)[(size_t)node * 8 + cq];

        float ax0 = 0.f, ay0 = 0.f, az0 = 0.f, aw0 = 0.f;
        float ax1 = 0.f, ay1 = 0.f, az1 = 0.f, aw1 = 0.f;
        int e = s0;
        if (full) {
            float2 f0 = x16f2[(size_t)pc0 * 8 + cq];
            float2 f1 = x16f2[(size_t)pc1 * 8 + cq];
            h4acc(f0, ax0, ay0, az0, aw0);
            h4acc(f1, ax1, ay1, az1, aw1);
            e = s0 + 16;
            for (; e + 15 < s1; e += 16) {
                int c0 = col[e + g];
                int c1 = col[e + 8 + g];
                float2 g0 = x16f2[(size_t)c0 * 8 + cq];
                float2 g1 = x16f2[(size_t)c1 * 8 + cq];
                h4acc(g0, ax0, ay0, az0, aw0);
                h4acc(g1, ax1, ay1, az1, aw1);
            }
        }
        for (int ee = e + g; ee < s1; ee += 8) {
            float2 f = x16f2[(size_t)col[ee] * 8 + cq];
            h4acc(f, ax0, ay0, az0, aw0);
        }
        float avx = ax0 + ax1, avy = ay0 + ay1, avz = az0 + az1, avw = aw0 + aw1;
        avx += __shfl_xor(avx, 8);  avy += __shfl_xor(avy, 8);
        avz += __shfl_xor(avz, 8);  avw += __shfl_xor(avw, 8);
        avx += __shfl_xor(avx, 16); avy += __shfl_xor(avy, 16);
        avz += __shfl_xor(avz, 16); avw += __shfl_xor(avw, 16);
        avx += __shfl_xor(avx, 32); avy += __shfl_xor(avy, 32);
        avz += __shfl_xor(avz, 32); avw += __shfl_xor(avw, 32);
        avx += sf.x; avy += sf.y; avz += sf.z; avw += sf.w;

        unsigned u0 = pkh2(avx, avy);
        unsigned u1 = pkh2(avz, avw);
        if (lane < 8)
            *reinterpret_cast<uint2*>(&aggL[wv][2 * cq]) = make_uint2(u0, u1);

        float sa = b1s[lane], sb = 0.f;
#pragma unroll
        for (int i = 0; i < 8; ++i) {
            uint2 A = *reinterpret_cast<const uint2*>(&aggL[wv][2 * i]);
            sa = fdot2u(A.x, W1s[(2 * i) * 64 + lane],     sa);
            sb = fdot2u(A.y, W1s[(2 * i + 1) * 64 + lane], sb);
        }
        float t = fmaxf(sa + sb, 0.f);

        float tt = __shfl_xor(t, 1);
        unsigned tp = pkh2((lane & 1) ? tt : t, (lane & 1) ? t : tt);
        if (!(lane & 1)) tL[wv][lane >> 1] = tp;

        float oa = b2s[lane], ob = 0.f;
#pragma unroll
        for (int q = 0; q < 32; q += 2) {
            uint2 T = *reinterpret_cast<const uint2*>(&tL[wv][q]);
            oa = fdot2u(T.x, W2s[q * 64 + lane],       oa);
            ob = fdot2u(T.y, W2s[(q + 1) * 64 + lane], ob);
        }
        h16[(size_t)node * 64 + lane] = __float2half(fmaxf(oa + ob, 0.f));

        node = nnode; s0 = s0n; s1 = s1n; full = fulln; pc0 = nc0; pc1 = nc1;
    }
}

// ============ layer 2: half4 gather(h16) + LDS-broadcast dot2-MLP2 -> out ============
// + cross-node col prefetch (first 16-edge batch: 4 col loads)
__global__ __launch_bounds__(256) void fused2(const float2* __restrict__ hf2,
                                              const int* __restrict__ P,
                                              const int* __restrict__ col,
                                              const unsigned* __restrict__ W3p,
                                              const float* __restrict__ b3,
                                              const unsigned* __restrict__ W4p,
                                              const float* __restrict__ b4,
                                              float* __restrict__ out) {
    __shared__ unsigned W3s[32 * 64];   // 8 KB
    __shared__ unsigned W4s[32 * 32];   // 4 KB
    __shared__ float b3s[64];
    __shared__ float b4s[32];
    __shared__ unsigned aggL[4][32];
    __shared__ unsigned tL[4][32];
    for (int i = threadIdx.x; i < 32 * 64; i += 256) W3s[i] = W3p[i];
    for (int i = threadIdx.x; i < 32 * 32; i += 256) W4s[i] = W4p[i];
    if (threadIdx.x < 64) b3s[threadIdx.x] = b3[threadIdx.x];
    if (threadIdx.x < 32) b4s[threadIdx.x] = b4[threadIdx.x];
    __syncthreads();

    int lane = threadIdx.x & 63;
    int cq = lane & 15;
    int g = lane >> 4;
    int wv = threadIdx.x >> 6;
    int gw = blockIdx.x * 4 + wv;
    int nwaves = gridDim.x * 4;

    int node = gw;
    int s0 = (node < NN) ? P[node * NSP1] : 0;
    int s1 = (node < NN) ? P[(node + 1) * NSP1] : 0;
    bool full = (node < NN) && (s0 + 15 < s1);
    int pc0 = 0, pc1 = 0, pc2 = 0, pc3 = 0;
    if (full) {
        pc0 = col[s0 + g];     pc1 = col[s0 + 4 + g];
        pc2 = col[s0 + 8 + g]; pc3 = col[s0 + 12 + g];
    }

    while (node < NN) {
        int nnode = node + nwaves;
        int s0n = (nnode < NN) ? P[nnode * NSP1] : 0;
        int s1n = (nnode < NN) ? P[(nnode + 1) * NSP1] : 0;
        bool fulln = (nnode < NN) && (s0n + 15 < s1n);
        int nc0 = 0, nc1 = 0, nc2 = 0, nc3 = 0;
        if (fulln) {
            nc0 = col[s0n + g];     nc1 = col[s0n + 4 + g];
            nc2 = col[s0n + 8 + g]; nc3 = col[s0n + 12 + g];
        }

        float2 sfr = hf2[(size_t)node * 16 + cq];

        float ax0 = 0.f, ay0 = 0.f, az0 = 0.f, aw0 = 0.f;
        float ax1 = 0.f, ay1 = 0.f, az1 = 0.f, aw1 = 0.f;
        float ax2 = 0.f, ay2 = 0.f, az2 = 0.f, aw2 = 0.f;
        float ax3 = 0.f, ay3 = 0.f, az3 = 0.f, aw3 = 0.f;
        int e = s0;
        if (full) {
            float2 f0 = hf2[(size_t)pc0 * 16 + cq];
            float2 f1 = hf2[(size_t)pc1 * 16 + cq];
            float2 f2 = hf2[(size_t)pc2 * 16 + cq];
            float2 f3 = hf2[(size_t)pc3 * 16 + cq];
            h4acc(f0, ax0, ay0, az0, aw0);
            h4acc(f1, ax1, ay1, az1, aw1);
            h4acc(f2, ax2, ay2, az2, aw2);
            h4acc(f3, ax3, ay3, az3, aw3);
            e = s0 + 16;
            for (; e + 15 < s1; e += 16) {
                int c0 = col[e + g];
                int c1 = col[e + 4 + g];
                int c2 = col[e + 8 + g];
                int c3 = col[e + 12 + g];
                float2 g0 = hf2[(size_t)c0 * 16 + cq];
                float2 g1 = hf2[(size_t)c1 * 16 + cq];
                float2 g2 = hf2[(size_t)c2 * 16 + cq];
                float2 g3 = hf2[(size_t)c3 * 16 + cq];
                h4acc(g0, ax0, ay0, az0, aw0);
                h4acc(g1, ax1, ay1, az1, aw1);
                h4acc(g2, ax2, ay2, az2, aw2);
                h4acc(g3, ax3, ay3, az3, aw3);
            }
        }
        for (int ee = e + g; ee < s1; ee += 4) {
            float2 f = hf2[(size_t)col[ee] * 16 + cq];
            h4acc(f, ax0, ay0, az0, aw0);
        }
        float avx = (ax0 + ax1) + (ax2 + ax3);
        float avy = (ay0 + ay1) + (ay2 + ay3);
        float avz = (az0 + az1) + (az2 + az3);
        float avw = (aw0 + aw1) + (aw2 + aw3);
        avx += __shfl_xor(avx, 16); avy += __shfl_xor(avy, 16);
        avz += __shfl_xor(avz, 16); avw += __shfl_xor(avw, 16);
        avx += __shfl_xor(avx, 32); avy += __shfl_xor(avy, 32);
        avz += __shfl_xor(avz, 32); avw += __shfl_xor(avw, 32);
        {
            __half2 lo = *reinterpret_cast<__half2*>(&sfr.x);
            __half2 hi = *reinterpret_cast<__half2*>(&sfr.y);
            float2 a = __half22float2(lo), b = __half22float2(hi);
            avx += a.x; avy += a.y; avz += b.x; avw += b.y;
        }

        unsigned u0 = pkh2(avx, avy);
        unsigned u1 = pkh2(avz, avw);
        if (lane < 16)
            *reinterpret_cast<uint2*>(&aggL[wv][2 * cq]) = make_uint2(u0, u1);

        float sa = b3s[lane], sb = 0.f;
#pragma unroll
        for (int i = 0; i < 16; ++i) {
            uint2 A = *reinterpret_cast<const uint2*>(&aggL[wv][2 * i]);
            sa = fdot2u(A.x, W3s[(2 * i) * 64 + lane],     sa);
            sb = fdot2u(A.y, W3s[(2 * i + 1) * 64 + lane], sb);
        }
        float t = fmaxf(sa + sb, 0.f);

        float tt = __shfl_xor(t, 1);
        unsigned tp = pkh2((lane & 1) ? tt : t, (lane & 1) ? t : tt);
        if (!(lane & 1)) tL[wv][lane >> 1] = tp;

        float oa = b4s[lane & 31], ob = 0.f;
#pragma unroll
        for (int q = 0; q < 32; q += 2) {
            uint2 T = *reinterpret_cast<const uint2*>(&tL[wv][q]);
            oa = fdot2u(T.x, W4s[q * 32 + (lane & 31)],       oa);
            ob = fdot2u(T.y, W4s[(q + 1) * 32 + (lane & 31)], ob);
        }
        if (lane < 32) out[(size_t)node * 32 + lane] = oa + ob;

        node = nnode; s0 = s0n; s1 = s1n; full = fulln;
        pc0 = nc0; pc1 = nc1; pc2 = nc2; pc3 = nc3;
    }
}

extern "C" void kernel_launch(void* const* d_in, const int* in_sizes, int n_in,
                              void* d_out, int out_size, void* d_ws, size_t ws_size,
                              hipStream_t stream) {
    const float* x  = (const float*)d_in[0];
    const int*   ei = (const int*)d_in[1];
    const float* W1 = (const float*)d_in[2];
    const float* b1 = (const float*)d_in[3];
    const float* W2 = (const float*)d_in[4];
    const float* b2 = (const float*)d_in[5];
    const float* W3 = (const float*)d_in[6];
    const float* b3 = (const float*)d_in[7];
    const float* W4 = (const float*)d_in[8];
    const float* b4 = (const float*)d_in[9];
    float* out = (float*)d_out;

    char* ws = (char*)d_ws;
    __half* h16   = (__half*)ws;                      ws += (size_t)NN * 64 * 2;           // 12.8 MB
    __half* x16   = (__half*)ws;                      ws += (size_t)NN * 32 * 2;           // 6.4 MB
    int*   col    = (int*)ws;                         ws += (size_t)NE * 4;                // 6.4 MB
    int*   P      = (int*)ws;                         ws += (size_t)(NN * NSP1 + 1) * 4;   // 3.2 MB
    int*   deg2   = (int*)ws;                         ws += (size_t)NN * NS * 4;           // 2.8 MB
    int*   segbuf = (int*)ws;                         ws += (size_t)NE * 4;                // 6.4 MB
    int* scanned  = (int*)ws;                         ws += (size_t)NN * 4;
    int*   bsums  = (int*)ws;                         ws += (size_t)NB * 4;
    int*  segcnt  = (int*)ws;                         ws += (size_t)NSEG * 4;
    int* segstart = (int*)ws;                         ws += (size_t)(NSEG + 1) * 4;
    int* cursorA  = (int*)ws;                         ws += (size_t)NSEG * 4;
    unsigned* W1p = (unsigned*)ws;                    ws += (size_t)16 * 64 * 4;
    unsigned* W2p = (unsigned*)ws;                    ws += (size_t)32 * 64 * 4;
    unsigned* W3p = (unsigned*)ws;                    ws += (size_t)32 * 64 * 4;
    unsigned* W4p = (unsigned*)ws;                    ws += (size_t)32 * 32 * 4;

    // ---- build: two-phase LDS-staged radix + merged cvt/pack ----
    (void)hipMemsetAsync(segcnt, 0, (size_t)NSEG * 4, stream);
    cvtpack_k<<<(NN * 16 + 255) / 256, 256, 0, stream>>>((const float2*)x, (__half2*)x16,
                                                         W1, W2, W3, W4, W1p, W2p, W3p, W4p);
    seghist_k<<<GRID_E, 256, 0, stream>>>(ei, segcnt);
    segscan_k<<<1, 512, 0, stream>>>(segcnt, segstart, cursorA);
    fillA_k<<<GRID_E, 256, 0, stream>>>(ei, cursorA, segbuf);
    deghist_k<<<NSEG, 256, 0, stream>>>(segbuf, segstart, deg2);
    scan1_k<<<NB, 256, 0, stream>>>(deg2, scanned, bsums);
    scan2_k<<<1, 512, 0, stream>>>(bsums);
    scan3b_k<<<NB, 256, 0, stream>>>(scanned, bsums, deg2, P);
    fillB_k<<<NSEG, 256, 0, stream>>>(segbuf, segstart, P, col);

    // ---- fused layers: LDS-broadcast dot2 MLP + cross-node col prefetch ----
    fused1<<<2048, 256, 0, stream>>>(x, (const float2*)x16, P, col,
                                     W1p, b1, W2p, b2, h16);
    fused2<<<2048, 256, 0, stream>>>((const float2*)h16, P, col,
                                     W3p, b3, W4p, b4, out);
}